// Round 7
// baseline (2189.480 us; speedup 1.0000x reference)
//
#include <hip/hip_runtime.h>
#include <hip/hip_bf16.h>

#define NN 8192
#define DD 768
#define HH 4
#define CC 192
#define KK 8
#define HC 768

typedef __attribute__((ext_vector_type(8))) short short8;
typedef __attribute__((ext_vector_type(4))) float floatx4;

static __device__ __forceinline__ short f2bf(float v) {
    unsigned u = __builtin_bit_cast(unsigned, v);
    u += 0x7fff + ((u >> 16) & 1);
    return (short)(u >> 16);
}
static __device__ __forceinline__ float bf2f(short s) {
    unsigned u = ((unsigned)(unsigned short)s) << 16;
    return __builtin_bit_cast(float, u);
}

// async global->LDS, 16B per lane, dest = wave-uniform base + lane*16
static __device__ __forceinline__ void gl16(const void* g, void* l) {
    __builtin_amdgcn_global_load_lds(
        (__attribute__((address_space(1))) void*)(void*)g,
        (__attribute__((address_space(3))) void*)l, 16, 0, 0);
}

// -------------------- fused BN + rownorm + bf16 hi/lo splits --------------
__global__ __launch_bounds__(256) void bnorm_kernel(const float* __restrict__ x,
    const float* __restrict__ g, const float* __restrict__ b,
    const float* __restrict__ rm, const float* __restrict__ rv,
    short* __restrict__ xbh, short* __restrict__ xbl,
    short* __restrict__ xnh, short* __restrict__ xnl)
{
    int i = blockIdx.x, t = threadIdx.x;
    __shared__ float red[256];
    float v[3];
    float ss = 0.f;
#pragma unroll
    for (int q = 0; q < 3; q++) {
        int d = t + q * 256;
        float xv = x[(size_t)i * DD + d];
        float vv = (xv - rm[d]) * rsqrtf(rv[d] + 1e-5f) * g[d] + b[d];
        v[q] = vv; ss += vv * vv;
    }
    red[t] = ss; __syncthreads();
    for (int s = 128; s; s >>= 1) { if (t < s) red[t] += red[t + s]; __syncthreads(); }
    float inv = 1.0f / (sqrtf(red[0]) + 1e-8f);
#pragma unroll
    for (int q = 0; q < 3; q++) {
        int d = t + q * 256;
        size_t idx = (size_t)i * DD + d;
        float vv = v[q];
        short h = f2bf(vv);
        xbh[idx] = h; xbl[idx] = f2bf(vv - bf2f(h));
        float nv = vv * inv;
        short nh = f2bf(nv);
        xnh[idx] = nh; xnl[idx] = f2bf(nv - bf2f(nh));
    }
}

// --------- all 6 weight transposes (hi/lo, W[KxP] -> Wt[PxK]) in one ------
__global__ __launch_bounds__(256) void wtrans6(
    const float* w0, short* o0h, short* o0l,   // res1 768x768
    const float* w1, short* o1h, short* o1l,   // g1   768x768
    const float* w2, short* o2h, short* o2l,   // g2   768x768
    const float* w3, short* o3h, short* o3l,   // res2 768x192
    const float* w4, short* o4h, short* o4l,   // g3   768x768
    const float* w5, short* o5h, short* o5l)   // g4   192x768
{
    int idx = blockIdx.x * 256 + threadIdx.x;
    const float* w; short* oh; short* ol; int K, P; int r;
    if (idx < 589824)            { w = w0; oh = o0h; ol = o0l; K = 768; P = 768; r = idx; }
    else if (idx < 2 * 589824)   { w = w1; oh = o1h; ol = o1l; K = 768; P = 768; r = idx - 589824; }
    else if (idx < 3 * 589824)   { w = w2; oh = o2h; ol = o2l; K = 768; P = 768; r = idx - 2 * 589824; }
    else if (idx < 3 * 589824 + 147456) { w = w3; oh = o3h; ol = o3l; K = 768; P = 192; r = idx - 3 * 589824; }
    else if (idx < 4 * 589824 + 147456) { w = w4; oh = o4h; ol = o4l; K = 768; P = 768; r = idx - 3 * 589824 - 147456; }
    else if (idx < 4 * 589824 + 2 * 147456) { w = w5; oh = o5h; ol = o5l; K = 192; P = 768; r = idx - 4 * 589824 - 147456; }
    else return;
    int p = r / K, k = r % K;
    float v = w[(size_t)k * P + p];
    short h = f2bf(v);
    oh[r] = h;
    ol[r] = f2bf(v - bf2f(h));
}

// ---------------- split-bf16 MFMA GEMM, C = A @ B^T, LDS-staged -----------
// C[row*Cstride + col] = sum + (col<biasN ? bias[col] : 0)
__global__ __launch_bounds__(256) void mfma_nt(
    const short* __restrict__ Ahi, const short* __restrict__ Alo,
    const short* __restrict__ Bhi, const short* __restrict__ Blo,
    const float* __restrict__ bias, int biasN, float* __restrict__ C,
    int M, int K, int P, int Cstride)
{
    __shared__ __attribute__((aligned(16))) short sAh[128 * 32];
    __shared__ __attribute__((aligned(16))) short sAl[128 * 32];
    __shared__ __attribute__((aligned(16))) short sBh[128 * 32];
    __shared__ __attribute__((aligned(16))) short sBl[128 * 32];
    int t = threadIdx.x;
    int wave = t >> 6, lane = t & 63;
    int wm = wave & 1, wn = wave >> 1;
    int i0 = blockIdx.y * 128, j0 = blockIdx.x * 128;
    int mrow = lane & 15, quad = lane >> 4;

    int srow = lane >> 2;
    int kg   = (lane & 3) ^ ((lane >> 3) & 3);
    int koff = kg * 8;
    int c0 = wave * 2, c1 = c0 + 1;
    int ar0 = i0 + c0 * 16 + srow, ar1 = i0 + c1 * 16 + srow;
    int br0 = j0 + c0 * 16 + srow, br1 = j0 + c1 * 16 + srow;
    if (br0 > P - 1) br0 = P - 1;
    if (br1 > P - 1) br1 = P - 1;
    const short* pAh0 = Ahi + (size_t)ar0 * K + koff;
    const short* pAh1 = Ahi + (size_t)ar1 * K + koff;
    const short* pAl0 = Alo + (size_t)ar0 * K + koff;
    const short* pAl1 = Alo + (size_t)ar1 * K + koff;
    const short* pBh0 = Bhi + (size_t)br0 * K + koff;
    const short* pBh1 = Bhi + (size_t)br1 * K + koff;
    const short* pBl0 = Blo + (size_t)br0 * K + koff;
    const short* pBl1 = Blo + (size_t)br1 * K + koff;
    short* dA0 = sAh + c0 * 512; short* dA1 = sAh + c1 * 512;
    short* dAl0 = sAl + c0 * 512; short* dAl1 = sAl + c1 * 512;
    short* dB0 = sBh + c0 * 512; short* dB1 = sBh + c1 * 512;
    short* dBl0 = sBl + c0 * 512; short* dBl1 = sBl + c1 * 512;

    floatx4 acc[4][4];
#pragma unroll
    for (int a = 0; a < 4; a++)
#pragma unroll
        for (int b = 0; b < 4; b++) acc[a][b] = (floatx4){0.f, 0.f, 0.f, 0.f};

    int aoff[4], boff[4];
#pragma unroll
    for (int mt = 0; mt < 4; mt++) {
        int r = wm * 64 + mt * 16 + mrow;
        aoff[mt] = r * 32 + (quad ^ ((r >> 1) & 3)) * 8;
    }
#pragma unroll
    for (int nt = 0; nt < 4; nt++) {
        int r = wn * 64 + nt * 16 + mrow;
        boff[nt] = r * 32 + (quad ^ ((r >> 1) & 3)) * 8;
    }

    for (int k0 = 0; k0 < K; k0 += 32) {
        gl16(pAh0 + k0, dA0);  gl16(pAh1 + k0, dA1);
        gl16(pAl0 + k0, dAl0); gl16(pAl1 + k0, dAl1);
        gl16(pBh0 + k0, dB0);  gl16(pBh1 + k0, dB1);
        gl16(pBl0 + k0, dBl0); gl16(pBl1 + k0, dBl1);
        __syncthreads();

        short8 ah[4], al[4], bh[4], bl[4];
#pragma unroll
        for (int mt = 0; mt < 4; mt++) {
            ah[mt] = *(const short8*)(sAh + aoff[mt]);
            al[mt] = *(const short8*)(sAl + aoff[mt]);
        }
#pragma unroll
        for (int nt = 0; nt < 4; nt++) {
            bh[nt] = *(const short8*)(sBh + boff[nt]);
            bl[nt] = *(const short8*)(sBl + boff[nt]);
        }
#pragma unroll
        for (int mt = 0; mt < 4; mt++)
#pragma unroll
            for (int nt = 0; nt < 4; nt++) {
                acc[mt][nt] = __builtin_amdgcn_mfma_f32_16x16x32_bf16(
                    ah[mt], bh[nt], acc[mt][nt], 0, 0, 0);
                acc[mt][nt] = __builtin_amdgcn_mfma_f32_16x16x32_bf16(
                    ah[mt], bl[nt], acc[mt][nt], 0, 0, 0);
                acc[mt][nt] = __builtin_amdgcn_mfma_f32_16x16x32_bf16(
                    al[mt], bh[nt], acc[mt][nt], 0, 0, 0);
            }
        __syncthreads();
    }

#pragma unroll
    for (int mt = 0; mt < 4; mt++)
#pragma unroll
        for (int nt = 0; nt < 4; nt++) {
            int col = j0 + wn * 64 + nt * 16 + mrow;
            if (col < P) {
                float bb = (bias && col < biasN) ? bias[col] : 0.f;
#pragma unroll
                for (int r = 0; r < 4; r++) {
                    int row = i0 + wm * 64 + mt * 16 + quad * 4 + r;
                    C[(size_t)row * Cstride + col] = acc[mt][nt][r] + bb;
                }
            }
        }
}

// ------ fused sim GEMM + per-tile top-9: no sim matrix materialization ----
// A = B = xn (hi/lo), K=768, P=8192. Emits per (row, 128-col tile) the
// sorted top-9 (value desc, index asc) to pv/pi[row*576 + rank*64 + tile].
__global__ __launch_bounds__(256) void mfma_topk(
    const short* __restrict__ Xh, const short* __restrict__ Xl,
    float* __restrict__ pv, int* __restrict__ pi)
{
    __shared__ __attribute__((aligned(16))) short smem[16384];  // 32 KB
    short* sAh = smem;
    short* sAl = smem + 4096;
    short* sBh = smem + 8192;
    short* sBl = smem + 12288;
    int t = threadIdx.x;
    int wave = t >> 6, lane = t & 63;
    int wm = wave & 1, wn = wave >> 1;
    int i0 = blockIdx.y * 128, j0 = blockIdx.x * 128;
    int mrow = lane & 15, quad = lane >> 4;

    int srow = lane >> 2;
    int kg   = (lane & 3) ^ ((lane >> 3) & 3);
    int koff = kg * 8;
    int c0 = wave * 2, c1 = c0 + 1;
    int ar0 = i0 + c0 * 16 + srow, ar1 = i0 + c1 * 16 + srow;
    int br0 = j0 + c0 * 16 + srow, br1 = j0 + c1 * 16 + srow;
    const short* pAh0 = Xh + (size_t)ar0 * DD + koff;
    const short* pAh1 = Xh + (size_t)ar1 * DD + koff;
    const short* pAl0 = Xl + (size_t)ar0 * DD + koff;
    const short* pAl1 = Xl + (size_t)ar1 * DD + koff;
    const short* pBh0 = Xh + (size_t)br0 * DD + koff;
    const short* pBh1 = Xh + (size_t)br1 * DD + koff;
    const short* pBl0 = Xl + (size_t)br0 * DD + koff;
    const short* pBl1 = Xl + (size_t)br1 * DD + koff;
    short* dA0 = sAh + c0 * 512; short* dA1 = sAh + c1 * 512;
    short* dAl0 = sAl + c0 * 512; short* dAl1 = sAl + c1 * 512;
    short* dB0 = sBh + c0 * 512; short* dB1 = sBh + c1 * 512;
    short* dBl0 = sBl + c0 * 512; short* dBl1 = sBl + c1 * 512;

    floatx4 acc[4][4];
#pragma unroll
    for (int a = 0; a < 4; a++)
#pragma unroll
        for (int b = 0; b < 4; b++) acc[a][b] = (floatx4){0.f, 0.f, 0.f, 0.f};

    int aoff[4], boff[4];
#pragma unroll
    for (int mt = 0; mt < 4; mt++) {
        int r = wm * 64 + mt * 16 + mrow;
        aoff[mt] = r * 32 + (quad ^ ((r >> 1) & 3)) * 8;
    }
#pragma unroll
    for (int nt = 0; nt < 4; nt++) {
        int r = wn * 64 + nt * 16 + mrow;
        boff[nt] = r * 32 + (quad ^ ((r >> 1) & 3)) * 8;
    }

    for (int k0 = 0; k0 < DD; k0 += 32) {
        gl16(pAh0 + k0, dA0);  gl16(pAh1 + k0, dA1);
        gl16(pAl0 + k0, dAl0); gl16(pAl1 + k0, dAl1);
        gl16(pBh0 + k0, dB0);  gl16(pBh1 + k0, dB1);
        gl16(pBl0 + k0, dBl0); gl16(pBl1 + k0, dBl1);
        __syncthreads();

        short8 ah[4], al[4], bh[4], bl[4];
#pragma unroll
        for (int mt = 0; mt < 4; mt++) {
            ah[mt] = *(const short8*)(sAh + aoff[mt]);
            al[mt] = *(const short8*)(sAl + aoff[mt]);
        }
#pragma unroll
        for (int nt = 0; nt < 4; nt++) {
            bh[nt] = *(const short8*)(sBh + boff[nt]);
            bl[nt] = *(const short8*)(sBl + boff[nt]);
        }
#pragma unroll
        for (int mt = 0; mt < 4; mt++)
#pragma unroll
            for (int nt = 0; nt < 4; nt++) {
                acc[mt][nt] = __builtin_amdgcn_mfma_f32_16x16x32_bf16(
                    ah[mt], bh[nt], acc[mt][nt], 0, 0, 0);
                acc[mt][nt] = __builtin_amdgcn_mfma_f32_16x16x32_bf16(
                    ah[mt], bl[nt], acc[mt][nt], 0, 0, 0);
                acc[mt][nt] = __builtin_amdgcn_mfma_f32_16x16x32_bf16(
                    al[mt], bh[nt], acc[mt][nt], 0, 0, 0);
            }
        __syncthreads();
    }

    // ---- epilogue: per-row top-9 over this block's 128 cols, 2 halves ----
    float* fl = (float*)smem;     // 64 x 128 fp32 = 32 KB
    for (int half = 0; half < 2; half++) {
        __syncthreads();
        if (wm == half) {
#pragma unroll
            for (int mt = 0; mt < 4; mt++)
#pragma unroll
                for (int nt = 0; nt < 4; nt++)
#pragma unroll
                    for (int r = 0; r < 4; r++)
                        fl[(mt * 16 + quad * 4 + r) * 128 + wn * 64 + nt * 16 + mrow]
                            = acc[mt][nt][r];
        }
        __syncthreads();
        for (int rr = 0; rr < 16; rr++) {
            int lrow = wave * 16 + rr;
            float va = fl[lrow * 128 + lane];
            float vb = fl[lrow * 128 + lane + 64];
            int ia = j0 + lane, ib = j0 + lane + 64;
            if (vb > va || (vb == va && ib < ia)) {
                float tv = va; va = vb; vb = tv;
                int ti = ia; ia = ib; ib = ti;
            }
            float ov_ = 0.f; int oi_ = 0;
#pragma unroll
            for (int r = 0; r < 9; r++) {
                float bv = va; int bi = ia;
#pragma unroll
                for (int off = 1; off < 64; off <<= 1) {
                    float w = __shfl_xor(bv, off);
                    int wi = __shfl_xor(bi, off);
                    if (w > bv || (w == bv && wi < bi)) { bv = w; bi = wi; }
                }
                if (ia == bi) { va = vb; ia = ib; vb = -3e38f; ib = 0x7fffffff; }
                if (lane == r) { ov_ = bv; oi_ = bi; }
            }
            if (lane < 9) {
                int grow = i0 + half * 64 + lrow;
                size_t pos = (size_t)grow * 576 + (size_t)lane * 64 + blockIdx.x;
                pv[pos] = ov_; pi[pos] = oi_;
            }
        }
    }
}

// stage 2: one wave per row merges 64 sorted 9-lists (lane = one tile's list)
__global__ __launch_bounds__(256) void topk2_kernel(const float* __restrict__ pv,
    const int* __restrict__ pi, int* __restrict__ nbr)
{
    int wave = threadIdx.x >> 6, lane = threadIdx.x & 63;
    int row = blockIdx.x * 4 + wave;
    size_t base = (size_t)row * 576;
    float v[9]; int id[9];
#pragma unroll
    for (int q = 0; q < 9; q++) {
        size_t pos = base + (size_t)q * 64 + lane;   // coalesced
        v[q] = pv[pos]; id[q] = pi[pos];
    }
    int myi = 0;
#pragma unroll
    for (int r = 0; r < 9; r++) {
        float bv = v[0]; int bi = id[0];
#pragma unroll
        for (int off = 1; off < 64; off <<= 1) {
            float ov = __shfl_xor(bv, off);
            int oi = __shfl_xor(bi, off);
            if (ov > bv || (ov == bv && oi < bi)) { bv = ov; bi = oi; }
        }
        if (id[0] == bi) {
#pragma unroll
            for (int q = 0; q < 8; q++) { v[q] = v[q + 1]; id[q] = id[q + 1]; }
            v[8] = -3e38f; id[8] = 0x7fffffff;
        }
        if (r >= 1 && lane == r - 1) myi = bi;   // rank 0 = self, dropped
    }
    if (lane < KK) nbr[(size_t)row * KK + lane] = myi;
}

// ------------------------------------------------------ edge building
__global__ __launch_bounds__(256) void count_kernel(const int* __restrict__ nbr,
                                                    int* __restrict__ deg, int* __restrict__ mfl)
{
    int i = blockIdx.x * 256 + threadIdx.x;
    if (i >= NN) return;
    atomicAdd(&deg[i], 1); // self loop
    int mm = 0;
#pragma unroll
    for (int k = 0; k < KK; k++) {
        int j = nbr[i * KK + k];
        atomicAdd(&deg[j], 1);
        if (j == i + 1) mm = 1;
    }
    if (i < NN - 1) {
        mfl[i] = !mm;
        if (!mm) { atomicAdd(&deg[i + 1], 1); atomicAdd(&deg[i], 1); }
    }
}

__global__ __launch_bounds__(256) void scan_kernel(const int* __restrict__ deg,
                                                   int* __restrict__ rowptr, int* __restrict__ cur)
{
    __shared__ int sums[256];
    int t = threadIdx.x;
    int loc[32];
    int base = t * 32;
    int s = 0;
#pragma unroll
    for (int q = 0; q < 32; q++) { loc[q] = s; s += deg[base + q]; }
    sums[t] = s; __syncthreads();
    for (int off = 1; off < 256; off <<= 1) {
        int v = (t >= off) ? sums[t - off] : 0;
        __syncthreads();
        sums[t] += v;
        __syncthreads();
    }
    int myoff = (t == 0) ? 0 : sums[t - 1];
#pragma unroll
    for (int q = 0; q < 32; q++) { int rp = myoff + loc[q]; rowptr[base + q] = rp; cur[base + q] = rp; }
    if (t == 255) rowptr[NN] = sums[255];
}

__global__ __launch_bounds__(256) void fill_kernel(const int* __restrict__ nbr,
    const int* __restrict__ mfl, int* __restrict__ cur, int* __restrict__ csr)
{
    int i = blockIdx.x * 256 + threadIdx.x;
    if (i >= NN) return;
    int pos = atomicAdd(&cur[i], 1); csr[pos] = i; // self
#pragma unroll
    for (int k = 0; k < KK; k++) {
        int j = nbr[i * KK + k];
        pos = atomicAdd(&cur[j], 1); csr[pos] = i;
    }
    if (i < NN - 1 && mfl[i]) {
        pos = atomicAdd(&cur[i + 1], 1); csr[pos] = i;
        pos = atomicAdd(&cur[i], 1); csr[pos] = i + 1;
    }
}

// --------------------------------------------------------- es/ed dots
__global__ __launch_bounds__(256) void esed_kernel(const float* __restrict__ h, int hst,
    const float* __restrict__ a_s, const float* __restrict__ a_d,
    float* __restrict__ es, float* __restrict__ ed)
{
    int i = blockIdx.x;
    int t = threadIdx.x;
    int w = t >> 6, lane = t & 63;
    const float* hr = h + (size_t)i * hst + w * CC;
    float ps = 0.f, pd = 0.f;
    for (int c = lane; c < CC; c += 64) {
        float x = hr[c];
        ps += x * a_s[w * CC + c];
        pd += x * a_d[w * CC + c];
    }
#pragma unroll
    for (int off = 32; off; off >>= 1) { ps += __shfl_down(ps, off); pd += __shfl_down(pd, off); }
    if (lane == 0) { es[i * HH + w] = ps; ed[i * HH + w] = pd; }
}

// ------- softmax-attention aggregate + bias + relu + residual + LN --------
__global__ __launch_bounds__(256) void agg_ln_kernel(const float* __restrict__ h, int hst,
    const float* __restrict__ es, const float* __restrict__ ed,
    const int* __restrict__ rowptr, const int* __restrict__ csr,
    const float* __restrict__ gb, const float* __restrict__ rres, int rst,
    const float* __restrict__ gamma, const float* __restrict__ beta,
    float* __restrict__ outp, short* __restrict__ ohi, short* __restrict__ olo,
    int Dm, int concat,
    const float* __restrict__ fcw, const float* __restrict__ fcb,
    float* __restrict__ fco)
{
    int j = blockIdx.x;
    int t = threadIdx.x;
    int lane = t & 63, wave = t >> 6;
    __shared__ int ssrc[256];
    __shared__ float sal[256 * 4];
    __shared__ float sred[1024];
    __shared__ float accs[768];
    int p0 = rowptr[j], p1 = rowptr[j + 1];
    int cnt = p1 - p0;
    float edj[4];
#pragma unroll
    for (int hd = 0; hd < 4; hd++) edj[hd] = ed[j * 4 + hd];

    float acc0 = 0.f, acc1 = 0.f, acc2 = 0.f;
    int d0 = t, d1 = t + 256, d2 = t + 512;
    int h0 = d0 / CC, h1_ = d1 / CC, h2_ = d2 / CC;

    if (cnt <= 256) {
        float e[4];
        if (t < cnt) {
            int s = csr[p0 + t];
            ssrc[t] = s;
#pragma unroll
            for (int hd = 0; hd < 4; hd++) {
                float ee = es[s * 4 + hd] + edj[hd];
                e[hd] = ee > 0.f ? ee : 0.2f * ee;
            }
        } else {
#pragma unroll
            for (int hd = 0; hd < 4; hd++) e[hd] = -1e30f;
        }
        float mh[4];
#pragma unroll
        for (int hd = 0; hd < 4; hd++) {
            float rv = e[hd];
#pragma unroll
            for (int off = 32; off; off >>= 1) rv = fmaxf(rv, __shfl_down(rv, off));
            if (lane == 0) sred[wave * 4 + hd] = rv;
        }
        __syncthreads();
#pragma unroll
        for (int hd = 0; hd < 4; hd++)
            mh[hd] = fmaxf(fmaxf(sred[hd], sred[4 + hd]), fmaxf(sred[8 + hd], sred[12 + hd]));
        __syncthreads();
        float ex[4];
#pragma unroll
        for (int hd = 0; hd < 4; hd++) {
            ex[hd] = (t < cnt) ? expf(e[hd] - mh[hd]) : 0.f;
            float rv = ex[hd];
#pragma unroll
            for (int off = 32; off; off >>= 1) rv += __shfl_down(rv, off);
            if (lane == 0) sred[wave * 4 + hd] = rv;
        }
        __syncthreads();
#pragma unroll
        for (int hd = 0; hd < 4; hd++) {
            float dh = sred[hd] + sred[4 + hd] + sred[8 + hd] + sred[12 + hd] + 1e-16f;
            if (t < cnt) sal[t * 4 + hd] = ex[hd] / dh;
        }
        __syncthreads();
        for (int e2 = 0; e2 < cnt; e2++) {
            const float* hs = h + (size_t)ssrc[e2] * hst;
            acc0 += sal[e2 * 4 + h0] * hs[d0];
            acc1 += sal[e2 * 4 + h1_] * hs[d1];
            acc2 += sal[e2 * 4 + h2_] * hs[d2];
        }
    } else {
        float mh[4] = {-1e30f, -1e30f, -1e30f, -1e30f};
        for (int p = p0 + t; p < p1; p += 256) {
            int s = csr[p];
#pragma unroll
            for (int hd = 0; hd < 4; hd++) {
                float e = es[s * 4 + hd] + edj[hd];
                e = e > 0.f ? e : 0.2f * e;
                mh[hd] = fmaxf(mh[hd], e);
            }
        }
#pragma unroll
        for (int hd = 0; hd < 4; hd++) sred[hd * 256 + t] = mh[hd];
        __syncthreads();
        for (int s2 = 128; s2; s2 >>= 1) {
            if (t < s2)
#pragma unroll
                for (int hd = 0; hd < 4; hd++)
                    sred[hd * 256 + t] = fmaxf(sred[hd * 256 + t], sred[hd * 256 + t + s2]);
            __syncthreads();
        }
#pragma unroll
        for (int hd = 0; hd < 4; hd++) mh[hd] = sred[hd * 256];
        __syncthreads();
        float sh[4] = {0.f, 0.f, 0.f, 0.f};
        for (int p = p0 + t; p < p1; p += 256) {
            int s = csr[p];
#pragma unroll
            for (int hd = 0; hd < 4; hd++) {
                float e = es[s * 4 + hd] + edj[hd];
                e = e > 0.f ? e : 0.2f * e;
                sh[hd] += expf(e - mh[hd]);
            }
        }
#pragma unroll
        for (int hd = 0; hd < 4; hd++) sred[hd * 256 + t] = sh[hd];
        __syncthreads();
        for (int s2 = 128; s2; s2 >>= 1) {
            if (t < s2)
#pragma unroll
                for (int hd = 0; hd < 4; hd++)
                    sred[hd * 256 + t] += sred[hd * 256 + t + s2];
            __syncthreads();
        }
        float dh[4];
#pragma unroll
        for (int hd = 0; hd < 4; hd++) dh[hd] = sred[hd * 256] + 1e-16f;
        __syncthreads();
        for (int p = p0; p < p1; p += 64) {
            int cn = min(64, p1 - p);
            if (t < cn) {
                int s = csr[p + t];
                ssrc[t] = s;
#pragma unroll
                for (int hd = 0; hd < 4; hd++) {
                    float e = es[s * 4 + hd] + edj[hd];
                    e = e > 0.f ? e : 0.2f * e;
                    sal[t * 4 + hd] = expf(e - mh[hd]) / dh[hd];
                }
            }
            __syncthreads();
            for (int e2 = 0; e2 < cn; e2++) {
                const float* hs = h + (size_t)ssrc[e2] * hst;
                acc0 += sal[e2 * 4 + h0] * hs[d0];
                acc1 += sal[e2 * 4 + h1_] * hs[d1];
                acc2 += sal[e2 * 4 + h2_] * hs[d2];
            }
            __syncthreads();
        }
    }

    if (concat) {
        float v0 = fmaxf(acc0 + gb[d0], 0.f) + rres[(size_t)j * rst + d0];
        float v1 = fmaxf(acc1 + gb[d1], 0.f) + rres[(size_t)j * rst + d1];
        float v2 = fmaxf(acc2 + gb[d2], 0.f) + rres[(size_t)j * rst + d2];
        __syncthreads();
        sred[t] = v0 + v1 + v2; __syncthreads();
        for (int s = 128; s; s >>= 1) { if (t < s) sred[t] += sred[t + s]; __syncthreads(); }
        float mu = sred[0] / 768.f;
        __syncthreads();
        float a0 = v0 - mu, a1 = v1 - mu, a2 = v2 - mu;
        sred[t] = a0 * a0 + a1 * a1 + a2 * a2; __syncthreads();
        for (int s = 128; s; s >>= 1) { if (t < s) sred[t] += sred[t + s]; __syncthreads(); }
        float rs = rsqrtf(sred[0] / 768.f + 1e-5f);
        size_t base = (size_t)j * 768;
        float w0 = a0 * rs * gamma[d0] + beta[d0];
        float w1 = a1 * rs * gamma[d1] + beta[d1];
        float w2 = a2 * rs * gamma[d2] + beta[d2];
        outp[base + d0] = w0; outp[base + d1] = w1; outp[base + d2] = w2;
        short hh;
        hh = f2bf(w0); ohi[base + d0] = hh; olo[base + d0] = f2bf(w0 - bf2f(hh));
        hh = f2bf(w1); ohi[base + d1] = hh; olo[base + d1] = f2bf(w1 - bf2f(hh));
        hh = f2bf(w2); ohi[base + d2] = hh; olo[base + d2] = f2bf(w2 - bf2f(hh));
    } else {
        accs[d0] = acc0; accs[d1] = acc1; accs[d2] = acc2;
        __syncthreads();
        float val = 0.f;
        if (t < CC)
            val = fmaxf((accs[t] + accs[t + CC] + accs[t + 2 * CC] + accs[t + 3 * CC]) * 0.25f
                        + gb[t], 0.f) + rres[(size_t)j * rst + t];
        __syncthreads();
        sred[t] = (t < CC) ? val : 0.f; __syncthreads();
        for (int s = 128; s; s >>= 1) { if (t < s) sred[t] += sred[t + s]; __syncthreads(); }
        float mu = sred[0] / (float)CC;
        __syncthreads();
        float a = val - mu;
        sred[t] = (t < CC) ? a * a : 0.f; __syncthreads();
        for (int s = 128; s; s >>= 1) { if (t < s) sred[t] += sred[t + s]; __syncthreads(); }
        float rs = rsqrtf(sred[0] / (float)CC + 1e-5f);
        float w = a * rs * ((t < CC) ? gamma[t] : 0.f) + ((t < CC) ? beta[t] : 0.f);
        if (t < CC) {
            size_t idx = (size_t)j * CC + t;
            if (outp) outp[idx] = w;
            if (ohi) {
                short hh = f2bf(w);
                ohi[idx] = hh; olo[idx] = f2bf(w - bf2f(hh));
            }
            accs[t] = w;
        }
        if (fco) {
            __syncthreads();
            if (t < 64) {
#pragma unroll
                for (int n = 0; n < 7; n++) {
                    float p = 0.f;
                    for (int d = t; d < CC; d += 64) p += accs[d] * fcw[d * 7 + n];
#pragma unroll
                    for (int off = 32; off; off >>= 1) p += __shfl_down(p, off);
                    if (t == 0) fco[(size_t)j * 7 + n] = p + fcb[n];
                }
            }
        }
    }
}

extern "C" void kernel_launch(void* const* d_in, const int* in_sizes, int n_in,
                              void* d_out, int out_size, void* d_ws, size_t ws_size,
                              hipStream_t stream)
{
    const float* x     = (const float*)d_in[0];
    const float* bn_g  = (const float*)d_in[1];
    const float* bn_b  = (const float*)d_in[2];
    const float* bn_rm = (const float*)d_in[3];
    const float* bn_rv = (const float*)d_in[4];
    const float* g_w[4]  = {(const float*)d_in[5], (const float*)d_in[9],
                            (const float*)d_in[13], (const float*)d_in[17]};
    const float* g_as[4] = {(const float*)d_in[6], (const float*)d_in[10],
                            (const float*)d_in[14], (const float*)d_in[18]};
    const float* g_ad[4] = {(const float*)d_in[7], (const float*)d_in[11],
                            (const float*)d_in[15], (const float*)d_in[19]};
    const float* g_b[4]  = {(const float*)d_in[8], (const float*)d_in[12],
                            (const float*)d_in[16], (const float*)d_in[20]};
    const float* res1_w = (const float*)d_in[21];
    const float* res1_b = (const float*)d_in[22];
    const float* res2_w = (const float*)d_in[23];
    const float* res2_b = (const float*)d_in[24];
    const float* ln_g[4] = {(const float*)d_in[25], (const float*)d_in[27],
                            (const float*)d_in[29], (const float*)d_in[31]};
    const float* ln_b[4] = {(const float*)d_in[26], (const float*)d_in[28],
                            (const float*)d_in[30], (const float*)d_in[32]};
    const float* fc_w = (const float*)d_in[33];
    const float* fc_b = (const float*)d_in[34];
    float* out = (float*)d_out;

    float* F = (float*)d_ws;
    float* ASIM = F; F += 16777216;  // PV/PI scratch -> HB1 (8192x1536) -> HB3 (8192x960)
    float* H1   = F; F += 6291456;
    float* HB24 = F; F += 6291456;   // HB2 then HB4 (8192x768)
    float* H2   = F; F += 6291456;
    float* H3   = F; F += 1572864;
    float* ES   = F; F += 32768;
    float* ED   = F; F += 32768;
    short* S = (short*)F;
    short* XNH = S; S += 6291456;
    short* XNL = S; S += 6291456;
    short* XAH = S; S += 6291456;
    short* XAL = S; S += 6291456;
    short* WT1H = S; S += 1179648;   // 1536 x 768
    short* WT1L = S; S += 1179648;
    short* WT2H = S; S += 589824;    // 768 x 768
    short* WT2L = S; S += 589824;
    short* WT3H = S; S += 737280;    // 960 x 768
    short* WT3L = S; S += 737280;
    short* WT4H = S; S += 147456;    // 768 x 192
    short* WT4L = S; S += 147456;
    int* I = (int*)S;
    int* NBR    = I; I += NN * KK;
    int* DEG    = I; I += NN;
    int* ROWPTR = I; I += NN + 8;
    int* CUR    = I; I += NN;
    int* MFL    = I; I += NN;
    int* CSR    = I; I += 131072;
    // topk candidate scratch lives in the (currently unused) ASIM region
    float* PV = ASIM;                        // 8192*576 floats = 18.9 MB
    int*   PI = (int*)(ASIM + 4718592);      // 8192*576 ints

    // 1. fused BN + rownorm + splits
    bnorm_kernel<<<NN, 256, 0, stream>>>(x, bn_g, bn_b, bn_rm, bn_rv,
                                         XAH, XAL, XNH, XNL);
    // 2. all weight transposes in one launch
    wtrans6<<<(4 * 589824 + 2 * 147456 + 255) / 256, 256, 0, stream>>>(
        res1_w, WT1H, WT1L,
        g_w[0], WT1H + 768 * 768, WT1L + 768 * 768,
        g_w[1], WT2H, WT2L,
        res2_w, WT3H, WT3L,
        g_w[2], WT3H + 192 * 768, WT3L + 192 * 768,
        g_w[3], WT4H, WT4L);
    // 3. fused sim GEMM + per-tile top-9, then merge
    mfma_topk<<<dim3(64, 64), 256, 0, stream>>>(XNH, XNL, PV, PI);
    topk2_kernel<<<NN / 4, 256, 0, stream>>>(PV, PI, NBR);
    // 4. edges -> CSR
    hipMemsetAsync(DEG, 0, NN * sizeof(int), stream);
    count_kernel<<<NN / 256, 256, 0, stream>>>(NBR, DEG, MFL);
    scan_kernel<<<1, 256, 0, stream>>>(DEG, ROWPTR, CUR);
    fill_kernel<<<NN / 256, 256, 0, stream>>>(NBR, MFL, CUR, CSR);
    // 5. layer 1: [r1 | h1] = xb @ [res1_w | g1_w], then agg+LN
    float* HB1 = ASIM;
    mfma_nt<<<dim3(12, NN / 128), 256, 0, stream>>>(XAH, XAL, WT1H, WT1L,
        res1_b, 768, HB1, NN, DD, 1536, 1536);
    esed_kernel<<<NN, 256, 0, stream>>>(HB1 + 768, 1536, g_as[0], g_ad[0], ES, ED);
    agg_ln_kernel<<<NN, 256, 0, stream>>>(HB1 + 768, 1536, ES, ED, ROWPTR, CSR,
        g_b[0], HB1, 1536, ln_g[0], ln_b[0], H1, XAH, XAL, HC, 1, nullptr, nullptr, nullptr);
    // 6. layer 2
    mfma_nt<<<dim3(6, NN / 128), 256, 0, stream>>>(XAH, XAL, WT2H, WT2L,
        nullptr, 0, HB24, NN, HC, HC, HC);
    esed_kernel<<<NN, 256, 0, stream>>>(HB24, HC, g_as[1], g_ad[1], ES, ED);
    agg_ln_kernel<<<NN, 256, 0, stream>>>(HB24, HC, ES, ED, ROWPTR, CSR,
        g_b[1], H1, HC, ln_g[1], ln_b[1], H2, XAH, XAL, HC, 1, nullptr, nullptr, nullptr);
    // 7. layer 3: [r2 | h3] = h2 @ [res2_w | g3_w]
    float* HB3 = ASIM;
    mfma_nt<<<dim3(8, NN / 128), 256, 0, stream>>>(XAH, XAL, WT3H, WT3L,
        res2_b, 192, HB3, NN, HC, 960, 960);
    esed_kernel<<<NN, 256, 0, stream>>>(HB3 + 192, 960, g_as[2], g_ad[2], ES, ED);
    agg_ln_kernel<<<NN, 256, 0, stream>>>(HB3 + 192, 960, ES, ED, ROWPTR, CSR,
        g_b[2], HB3, 960, ln_g[2], ln_b[2], H3, XAH, XAL, CC, 0, nullptr, nullptr, nullptr);
    // 8. layer 4 (K=192) + fused final FC
    mfma_nt<<<dim3(6, NN / 128), 256, 0, stream>>>(XAH, XAL, WT4H, WT4L,
        nullptr, 0, HB24, NN, CC, HC, HC);
    esed_kernel<<<NN, 256, 0, stream>>>(HB24, HC, g_as[3], g_ad[3], ES, ED);
    agg_ln_kernel<<<NN, 256, 0, stream>>>(HB24, HC, ES, ED, ROWPTR, CSR,
        g_b[3], H3, CC, ln_g[3], ln_b[3], nullptr, nullptr, nullptr, CC, 0, fc_w, fc_b, out);
}

// Round 8
// 1207.993 us; speedup vs baseline: 1.8125x; 1.8125x over previous
//
#include <hip/hip_runtime.h>
#include <hip/hip_bf16.h>

#define NN 8192
#define DD 768
#define HH 4
#define CC 192
#define KK 8
#define HC 768

typedef __attribute__((ext_vector_type(8))) short short8;
typedef __attribute__((ext_vector_type(4))) float floatx4;

static __device__ __forceinline__ short f2bf(float v) {
    unsigned u = __builtin_bit_cast(unsigned, v);
    u += 0x7fff + ((u >> 16) & 1);
    return (short)(u >> 16);
}
static __device__ __forceinline__ float bf2f(short s) {
    unsigned u = ((unsigned)(unsigned short)s) << 16;
    return __builtin_bit_cast(float, u);
}

// async global->LDS, 16B per lane, dest = wave-uniform base + lane*16
static __device__ __forceinline__ void gl16(const void* g, void* l) {
    __builtin_amdgcn_global_load_lds(
        (__attribute__((address_space(1))) void*)(void*)g,
        (__attribute__((address_space(3))) void*)l, 16, 0, 0);
}

// -------------------- fused BN + rownorm + bf16 hi/lo splits --------------
__global__ __launch_bounds__(256) void bnorm_kernel(const float* __restrict__ x,
    const float* __restrict__ g, const float* __restrict__ b,
    const float* __restrict__ rm, const float* __restrict__ rv,
    short* __restrict__ xbh, short* __restrict__ xbl,
    short* __restrict__ xnh, short* __restrict__ xnl)
{
    int i = blockIdx.x, t = threadIdx.x;
    __shared__ float red[256];
    float v[3];
    float ss = 0.f;
#pragma unroll
    for (int q = 0; q < 3; q++) {
        int d = t + q * 256;
        float xv = x[(size_t)i * DD + d];
        float vv = (xv - rm[d]) * rsqrtf(rv[d] + 1e-5f) * g[d] + b[d];
        v[q] = vv; ss += vv * vv;
    }
    red[t] = ss; __syncthreads();
    for (int s = 128; s; s >>= 1) { if (t < s) red[t] += red[t + s]; __syncthreads(); }
    float inv = 1.0f / (sqrtf(red[0]) + 1e-8f);
#pragma unroll
    for (int q = 0; q < 3; q++) {
        int d = t + q * 256;
        size_t idx = (size_t)i * DD + d;
        float vv = v[q];
        short h = f2bf(vv);
        xbh[idx] = h; xbl[idx] = f2bf(vv - bf2f(h));
        float nv = vv * inv;
        short nh = f2bf(nv);
        xnh[idx] = nh; xnl[idx] = f2bf(nv - bf2f(nh));
    }
}

// --------- all 6 weight transposes (hi/lo, W[KxP] -> Wt[PxK]) in one ------
__global__ __launch_bounds__(256) void wtrans6(
    const float* w0, short* o0h, short* o0l,   // res1 768x768
    const float* w1, short* o1h, short* o1l,   // g1   768x768
    const float* w2, short* o2h, short* o2l,   // g2   768x768
    const float* w3, short* o3h, short* o3l,   // res2 768x192
    const float* w4, short* o4h, short* o4l,   // g3   768x768
    const float* w5, short* o5h, short* o5l)   // g4   192x768
{
    int idx = blockIdx.x * 256 + threadIdx.x;
    const float* w; short* oh; short* ol; int K, P; int r;
    if (idx < 589824)            { w = w0; oh = o0h; ol = o0l; K = 768; P = 768; r = idx; }
    else if (idx < 2 * 589824)   { w = w1; oh = o1h; ol = o1l; K = 768; P = 768; r = idx - 589824; }
    else if (idx < 3 * 589824)   { w = w2; oh = o2h; ol = o2l; K = 768; P = 768; r = idx - 2 * 589824; }
    else if (idx < 3 * 589824 + 147456) { w = w3; oh = o3h; ol = o3l; K = 768; P = 192; r = idx - 3 * 589824; }
    else if (idx < 4 * 589824 + 147456) { w = w4; oh = o4h; ol = o4l; K = 768; P = 768; r = idx - 3 * 589824 - 147456; }
    else if (idx < 4 * 589824 + 2 * 147456) { w = w5; oh = o5h; ol = o5l; K = 192; P = 768; r = idx - 4 * 589824 - 147456; }
    else return;
    int p = r / K, k = r % K;
    float v = w[(size_t)k * P + p];
    short h = f2bf(v);
    oh[r] = h;
    ol[r] = f2bf(v - bf2f(h));
}

// ---------------- split-bf16 MFMA GEMM, C = A @ B^T, LDS-staged -----------
// cols [0,bfoff): fp32 -> C (stride Cstride, +bias for col<biasN)
// cols [bfoff,P): bf16 -> Cbf at col-bfoff (stride bfstride)
// optional fused es/ed partial dots (a_s/a_d [4][192], h region starts hoff)
__global__ __launch_bounds__(256) void mfma_nt(
    const short* __restrict__ Ahi, const short* __restrict__ Alo,
    const short* __restrict__ Bhi, const short* __restrict__ Blo,
    const float* __restrict__ bias, int biasN,
    float* __restrict__ C, int Cstride,
    short* __restrict__ Cbf, int bfoff, int bfstride,
    const float* __restrict__ a_s, const float* __restrict__ a_d,
    float* __restrict__ es, float* __restrict__ ed, int hoff,
    int M, int K, int P)
{
    __shared__ __attribute__((aligned(16))) short sAh[128 * 32];
    __shared__ __attribute__((aligned(16))) short sAl[128 * 32];
    __shared__ __attribute__((aligned(16))) short sBh[128 * 32];
    __shared__ __attribute__((aligned(16))) short sBl[128 * 32];
    int t = threadIdx.x;
    int wave = t >> 6, lane = t & 63;
    int wm = wave & 1, wn = wave >> 1;
    int i0 = blockIdx.y * 128, j0 = blockIdx.x * 128;
    int mrow = lane & 15, quad = lane >> 4;

    int srow = lane >> 2;
    int kg   = (lane & 3) ^ ((lane >> 3) & 3);
    int koff = kg * 8;
    int c0 = wave * 2, c1 = c0 + 1;
    int ar0 = i0 + c0 * 16 + srow, ar1 = i0 + c1 * 16 + srow;
    int br0 = j0 + c0 * 16 + srow, br1 = j0 + c1 * 16 + srow;
    if (br0 > P - 1) br0 = P - 1;
    if (br1 > P - 1) br1 = P - 1;
    const short* pAh0 = Ahi + (size_t)ar0 * K + koff;
    const short* pAh1 = Ahi + (size_t)ar1 * K + koff;
    const short* pAl0 = Alo + (size_t)ar0 * K + koff;
    const short* pAl1 = Alo + (size_t)ar1 * K + koff;
    const short* pBh0 = Bhi + (size_t)br0 * K + koff;
    const short* pBh1 = Bhi + (size_t)br1 * K + koff;
    const short* pBl0 = Blo + (size_t)br0 * K + koff;
    const short* pBl1 = Blo + (size_t)br1 * K + koff;
    short* dA0 = sAh + c0 * 512; short* dA1 = sAh + c1 * 512;
    short* dAl0 = sAl + c0 * 512; short* dAl1 = sAl + c1 * 512;
    short* dB0 = sBh + c0 * 512; short* dB1 = sBh + c1 * 512;
    short* dBl0 = sBl + c0 * 512; short* dBl1 = sBl + c1 * 512;

    floatx4 acc[4][4];
#pragma unroll
    for (int a = 0; a < 4; a++)
#pragma unroll
        for (int b = 0; b < 4; b++) acc[a][b] = (floatx4){0.f, 0.f, 0.f, 0.f};

    int aoff[4], boff[4];
#pragma unroll
    for (int mt = 0; mt < 4; mt++) {
        int r = wm * 64 + mt * 16 + mrow;
        aoff[mt] = r * 32 + (quad ^ ((r >> 1) & 3)) * 8;
    }
#pragma unroll
    for (int nt = 0; nt < 4; nt++) {
        int r = wn * 64 + nt * 16 + mrow;
        boff[nt] = r * 32 + (quad ^ ((r >> 1) & 3)) * 8;
    }

    for (int k0 = 0; k0 < K; k0 += 32) {
        gl16(pAh0 + k0, dA0);  gl16(pAh1 + k0, dA1);
        gl16(pAl0 + k0, dAl0); gl16(pAl1 + k0, dAl1);
        gl16(pBh0 + k0, dB0);  gl16(pBh1 + k0, dB1);
        gl16(pBl0 + k0, dBl0); gl16(pBl1 + k0, dBl1);
        __syncthreads();

        short8 ah[4], al[4], bh[4], bl[4];
#pragma unroll
        for (int mt = 0; mt < 4; mt++) {
            ah[mt] = *(const short8*)(sAh + aoff[mt]);
            al[mt] = *(const short8*)(sAl + aoff[mt]);
        }
#pragma unroll
        for (int nt = 0; nt < 4; nt++) {
            bh[nt] = *(const short8*)(sBh + boff[nt]);
            bl[nt] = *(const short8*)(sBl + boff[nt]);
        }
#pragma unroll
        for (int mt = 0; mt < 4; mt++)
#pragma unroll
            for (int nt = 0; nt < 4; nt++) {
                acc[mt][nt] = __builtin_amdgcn_mfma_f32_16x16x32_bf16(
                    ah[mt], bh[nt], acc[mt][nt], 0, 0, 0);
                acc[mt][nt] = __builtin_amdgcn_mfma_f32_16x16x32_bf16(
                    ah[mt], bl[nt], acc[mt][nt], 0, 0, 0);
                acc[mt][nt] = __builtin_amdgcn_mfma_f32_16x16x32_bf16(
                    al[mt], bh[nt], acc[mt][nt], 0, 0, 0);
            }
        __syncthreads();
    }

#pragma unroll
    for (int mt = 0; mt < 4; mt++)
#pragma unroll
        for (int nt = 0; nt < 4; nt++) {
            int col = j0 + wn * 64 + nt * 16 + mrow;
            if (col < P) {
                if (col < bfoff) {
                    float bb = (bias && col < biasN) ? bias[col] : 0.f;
#pragma unroll
                    for (int r = 0; r < 4; r++) {
                        int row = i0 + wm * 64 + mt * 16 + quad * 4 + r;
                        C[(size_t)row * Cstride + col] = acc[mt][nt][r] + bb;
                    }
                } else {
#pragma unroll
                    for (int r = 0; r < 4; r++) {
                        int row = i0 + wm * 64 + mt * 16 + quad * 4 + r;
                        Cbf[(size_t)row * bfstride + col - bfoff] = f2bf(acc[mt][nt][r]);
                    }
                }
            }
        }

    // fused es/ed partial dots: wave's 64-col window lies in one head
    if (a_s) {
        int base = j0 + wn * 64;
        if (base >= hoff && base + 64 <= P) {
            int head = (base - hoff) / CC;
            int cb = (base - hoff) % CC;
#pragma unroll
            for (int mt = 0; mt < 4; mt++) {
                float ps[4] = {0.f, 0.f, 0.f, 0.f};
                float pd[4] = {0.f, 0.f, 0.f, 0.f};
#pragma unroll
                for (int nt = 0; nt < 4; nt++) {
                    int c = cb + nt * 16 + mrow;
                    float as_ = a_s[head * CC + c];
                    float ad_ = a_d[head * CC + c];
#pragma unroll
                    for (int r = 0; r < 4; r++) {
                        ps[r] += acc[mt][nt][r] * as_;
                        pd[r] += acc[mt][nt][r] * ad_;
                    }
                }
#pragma unroll
                for (int off = 1; off < 16; off <<= 1)
#pragma unroll
                    for (int r = 0; r < 4; r++) {
                        ps[r] += __shfl_xor(ps[r], off);
                        pd[r] += __shfl_xor(pd[r], off);
                    }
                if (mrow == 0) {
#pragma unroll
                    for (int r = 0; r < 4; r++) {
                        int row = i0 + wm * 64 + mt * 16 + quad * 4 + r;
                        atomicAdd(&es[row * 4 + head], ps[r]);
                        atomicAdd(&ed[row * 4 + head], pd[r]);
                    }
                }
            }
        }
    }
}

// -------------------------------------------------------------- top-k
__device__ __forceinline__ bool tk_try(float* v, int* id, float xv, int xi)
{
    if (xv > v[8] || (xv == v[8] && xi < id[8])) {
        v[8] = xv; id[8] = xi;
#pragma unroll
        for (int p = 8; p > 0; p--) {
            if (v[p] > v[p - 1] || (v[p] == v[p - 1] && id[p] < id[p - 1])) {
                float tv = v[p]; v[p] = v[p - 1]; v[p - 1] = tv;
                int ti2 = id[p]; id[p] = id[p - 1]; id[p - 1] = ti2;
            } else break;
        }
        return true;
    }
    return false;
}

// stage 1: one wave per (row, 1024-col segment) -> sorted segment top-9.
__global__ __launch_bounds__(256) void topk1_kernel(const float* __restrict__ sim,
    float* __restrict__ pv, int* __restrict__ pi)
{
    int wave = threadIdx.x >> 6, lane = threadIdx.x & 63;
    int task = blockIdx.x * 4 + wave;
    int row = task >> 3, seg = task & 7;
    const float4* p4 = (const float4*)(sim + (size_t)row * NN + seg * 1024);

    float4 f0 = p4[lane], f1 = p4[lane + 64], f2 = p4[lane + 128], f3 = p4[lane + 192];
    float v[9]; int id[9];
#pragma unroll
    for (int q = 0; q < 9; q++) { v[q] = -3e38f; id[q] = 0x7fffffff; }
    int jb = seg * 1024 + lane * 4;
#pragma unroll
    for (int g = 0; g < 4; g++) {
        float4 f = g == 0 ? f0 : (g == 1 ? f1 : (g == 2 ? f2 : f3));
        float gm = fmaxf(fmaxf(f.x, f.y), fmaxf(f.z, f.w));
        if (gm >= v[8]) {
            int j = jb + g * 256;
            tk_try(v, id, f.x, j);
            tk_try(v, id, f.y, j + 1);
            tk_try(v, id, f.z, j + 2);
            tk_try(v, id, f.w, j + 3);
        }
    }
    float wv = -3e38f; int wi = 0x7fffffff;
#pragma unroll
    for (int r = 0; r < 9; r++) {
        float bv = v[0]; int bi = id[0];
#pragma unroll
        for (int off = 1; off < 64; off <<= 1) {
            float ov = __shfl_xor(bv, off);
            int oi = __shfl_xor(bi, off);
            if (ov > bv || (ov == bv && oi < bi)) { bv = ov; bi = oi; }
        }
        if (id[0] == bi) {
#pragma unroll
            for (int q = 0; q < 8; q++) { v[q] = v[q + 1]; id[q] = id[q + 1]; }
            v[8] = -3e38f; id[8] = 0x7fffffff;
        }
        if (lane == r) { wv = bv; wi = bi; }
    }
    if (lane < 9) {
        size_t o = (size_t)task * 9 + lane;
        pv[o] = wv; pi[o] = wi;
    }
}

// stage 2: one wave per row merges 8 sorted 9-lists (72 candidates).
__global__ __launch_bounds__(256) void topk2_kernel(const float* __restrict__ pv,
    const int* __restrict__ pi, int* __restrict__ nbr, int r0)
{
    int wave = threadIdx.x >> 6, lane = threadIdx.x & 63;
    int row = blockIdx.x * 4 + wave;
    size_t base = (size_t)row * 72;
    float v[2]; int id[2];
    v[0] = -3e38f; id[0] = 0x7fffffff;
    v[1] = -3e38f; id[1] = 0x7fffffff;
    if (lane < 72) { v[0] = pv[base + lane]; id[0] = pi[base + lane]; }
    if (lane < 8)  { v[1] = pv[base + 64 + lane]; id[1] = pi[base + 64 + lane]; }
    if (v[1] > v[0] || (v[1] == v[0] && id[1] < id[0])) {
        float tv = v[0]; v[0] = v[1]; v[1] = tv;
        int ti = id[0]; id[0] = id[1]; id[1] = ti;
    }
    int myi = 0;
#pragma unroll
    for (int r = 0; r < 9; r++) {
        float bv = v[0]; int bi = id[0];
#pragma unroll
        for (int off = 1; off < 64; off <<= 1) {
            float ov = __shfl_xor(bv, off);
            int oi = __shfl_xor(bi, off);
            if (ov > bv || (ov == bv && oi < bi)) { bv = ov; bi = oi; }
        }
        if (id[0] == bi) {
            v[0] = v[1]; id[0] = id[1];
            v[1] = -3e38f; id[1] = 0x7fffffff;
        }
        if (r >= 1 && lane == r - 1) myi = bi;
    }
    if (lane < KK) nbr[(size_t)(r0 + row) * KK + lane] = myi;
}

// ------------------------------------------------------ edge building
__global__ __launch_bounds__(256) void count_kernel(const int* __restrict__ nbr,
                                                    int* __restrict__ deg, int* __restrict__ mfl)
{
    int i = blockIdx.x * 256 + threadIdx.x;
    if (i >= NN) return;
    atomicAdd(&deg[i], 1); // self loop
    int mm = 0;
#pragma unroll
    for (int k = 0; k < KK; k++) {
        int j = nbr[i * KK + k];
        atomicAdd(&deg[j], 1);
        if (j == i + 1) mm = 1;
    }
    if (i < NN - 1) {
        mfl[i] = !mm;
        if (!mm) { atomicAdd(&deg[i + 1], 1); atomicAdd(&deg[i], 1); }
    }
}

__global__ __launch_bounds__(256) void scan_kernel(const int* __restrict__ deg,
                                                   int* __restrict__ rowptr, int* __restrict__ cur)
{
    __shared__ int sums[256];
    int t = threadIdx.x;
    int loc[32];
    int base = t * 32;
    int s = 0;
#pragma unroll
    for (int q = 0; q < 32; q++) { loc[q] = s; s += deg[base + q]; }
    sums[t] = s; __syncthreads();
    for (int off = 1; off < 256; off <<= 1) {
        int v = (t >= off) ? sums[t - off] : 0;
        __syncthreads();
        sums[t] += v;
        __syncthreads();
    }
    int myoff = (t == 0) ? 0 : sums[t - 1];
#pragma unroll
    for (int q = 0; q < 32; q++) { int rp = myoff + loc[q]; rowptr[base + q] = rp; cur[base + q] = rp; }
    if (t == 255) rowptr[NN] = sums[255];
}

__global__ __launch_bounds__(256) void fill_kernel(const int* __restrict__ nbr,
    const int* __restrict__ mfl, int* __restrict__ cur, int* __restrict__ csr)
{
    int i = blockIdx.x * 256 + threadIdx.x;
    if (i >= NN) return;
    int pos = atomicAdd(&cur[i], 1); csr[pos] = i; // self
#pragma unroll
    for (int k = 0; k < KK; k++) {
        int j = nbr[i * KK + k];
        pos = atomicAdd(&cur[j], 1); csr[pos] = i;
    }
    if (i < NN - 1 && mfl[i]) {
        pos = atomicAdd(&cur[i + 1], 1); csr[pos] = i;
        pos = atomicAdd(&cur[i], 1); csr[pos] = i + 1;
    }
}

// ------- softmax-attention aggregate (bf16 h) + relu + residual + LN ------
__global__ __launch_bounds__(256) void agg_ln_kernel(const short* __restrict__ h, int hst,
    const float* __restrict__ es, const float* __restrict__ ed,
    const int* __restrict__ rowptr, const int* __restrict__ csr,
    const float* __restrict__ gb, const float* __restrict__ rres, int rst,
    const float* __restrict__ gamma, const float* __restrict__ beta,
    float* __restrict__ outp, short* __restrict__ ohi, short* __restrict__ olo,
    int Dm, int concat,
    const float* __restrict__ fcw, const float* __restrict__ fcb,
    float* __restrict__ fco)
{
    int j = blockIdx.x;
    int t = threadIdx.x;
    int lane = t & 63, wave = t >> 6;
    __shared__ int ssrc[256];
    __shared__ float sal[256 * 4];
    __shared__ float sred[1024];
    __shared__ float accs[768];
    int p0 = rowptr[j], p1 = rowptr[j + 1];
    int cnt = p1 - p0;
    float edj[4];
#pragma unroll
    for (int hd = 0; hd < 4; hd++) edj[hd] = ed[j * 4 + hd];

    float acc0 = 0.f, acc1 = 0.f, acc2 = 0.f;
    int d0 = t, d1 = t + 256, d2 = t + 512;
    int h0 = d0 / CC, h1_ = d1 / CC, h2_ = d2 / CC;

    if (cnt <= 256) {
        float e[4];
        if (t < cnt) {
            int s = csr[p0 + t];
            ssrc[t] = s;
#pragma unroll
            for (int hd = 0; hd < 4; hd++) {
                float ee = es[s * 4 + hd] + edj[hd];
                e[hd] = ee > 0.f ? ee : 0.2f * ee;
            }
        } else {
#pragma unroll
            for (int hd = 0; hd < 4; hd++) e[hd] = -1e30f;
        }
        float mh[4];
#pragma unroll
        for (int hd = 0; hd < 4; hd++) {
            float rv = e[hd];
#pragma unroll
            for (int off = 32; off; off >>= 1) rv = fmaxf(rv, __shfl_down(rv, off));
            if (lane == 0) sred[wave * 4 + hd] = rv;
        }
        __syncthreads();
#pragma unroll
        for (int hd = 0; hd < 4; hd++)
            mh[hd] = fmaxf(fmaxf(sred[hd], sred[4 + hd]), fmaxf(sred[8 + hd], sred[12 + hd]));
        __syncthreads();
        float ex[4];
#pragma unroll
        for (int hd = 0; hd < 4; hd++) {
            ex[hd] = (t < cnt) ? expf(e[hd] - mh[hd]) : 0.f;
            float rv = ex[hd];
#pragma unroll
            for (int off = 32; off; off >>= 1) rv += __shfl_down(rv, off);
            if (lane == 0) sred[wave * 4 + hd] = rv;
        }
        __syncthreads();
#pragma unroll
        for (int hd = 0; hd < 4; hd++) {
            float dh = sred[hd] + sred[4 + hd] + sred[8 + hd] + sred[12 + hd] + 1e-16f;
            if (t < cnt) sal[t * 4 + hd] = ex[hd] / dh;
        }
        __syncthreads();
        for (int e2 = 0; e2 < cnt; e2++) {
            const short* hs = h + (size_t)ssrc[e2] * hst;
            acc0 += sal[e2 * 4 + h0] * bf2f(hs[d0]);
            acc1 += sal[e2 * 4 + h1_] * bf2f(hs[d1]);
            acc2 += sal[e2 * 4 + h2_] * bf2f(hs[d2]);
        }
    } else {
        float mh[4] = {-1e30f, -1e30f, -1e30f, -1e30f};
        for (int p = p0 + t; p < p1; p += 256) {
            int s = csr[p];
#pragma unroll
            for (int hd = 0; hd < 4; hd++) {
                float e = es[s * 4 + hd] + edj[hd];
                e = e > 0.f ? e : 0.2f * e;
                mh[hd] = fmaxf(mh[hd], e);
            }
        }
#pragma unroll
        for (int hd = 0; hd < 4; hd++) sred[hd * 256 + t] = mh[hd];
        __syncthreads();
        for (int s2 = 128; s2; s2 >>= 1) {
            if (t < s2)
#pragma unroll
                for (int hd = 0; hd < 4; hd++)
                    sred[hd * 256 + t] = fmaxf(sred[hd * 256 + t], sred[hd * 256 + t + s2]);
            __syncthreads();
        }
#pragma unroll
        for (int hd = 0; hd < 4; hd++) mh[hd] = sred[hd * 256];
        __syncthreads();
        float sh[4] = {0.f, 0.f, 0.f, 0.f};
        for (int p = p0 + t; p < p1; p += 256) {
            int s = csr[p];
#pragma unroll
            for (int hd = 0; hd < 4; hd++) {
                float e = es[s * 4 + hd] + edj[hd];
                e = e > 0.f ? e : 0.2f * e;
                sh[hd] += expf(e - mh[hd]);
            }
        }
#pragma unroll
        for (int hd = 0; hd < 4; hd++) sred[hd * 256 + t] = sh[hd];
        __syncthreads();
        for (int s2 = 128; s2; s2 >>= 1) {
            if (t < s2)
#pragma unroll
                for (int hd = 0; hd < 4; hd++)
                    sred[hd * 256 + t] += sred[hd * 256 + t + s2];
            __syncthreads();
        }
        float dh[4];
#pragma unroll
        for (int hd = 0; hd < 4; hd++) dh[hd] = sred[hd * 256] + 1e-16f;
        __syncthreads();
        for (int p = p0; p < p1; p += 64) {
            int cn = min(64, p1 - p);
            if (t < cn) {
                int s = csr[p + t];
                ssrc[t] = s;
#pragma unroll
                for (int hd = 0; hd < 4; hd++) {
                    float e = es[s * 4 + hd] + edj[hd];
                    e = e > 0.f ? e : 0.2f * e;
                    sal[t * 4 + hd] = expf(e - mh[hd]) / dh[hd];
                }
            }
            __syncthreads();
            for (int e2 = 0; e2 < cn; e2++) {
                const short* hs = h + (size_t)ssrc[e2] * hst;
                acc0 += sal[e2 * 4 + h0] * bf2f(hs[d0]);
                acc1 += sal[e2 * 4 + h1_] * bf2f(hs[d1]);
                acc2 += sal[e2 * 4 + h2_] * bf2f(hs[d2]);
            }
            __syncthreads();
        }
    }

    if (concat) {
        float v0 = fmaxf(acc0 + gb[d0], 0.f) + rres[(size_t)j * rst + d0];
        float v1 = fmaxf(acc1 + gb[d1], 0.f) + rres[(size_t)j * rst + d1];
        float v2 = fmaxf(acc2 + gb[d2], 0.f) + rres[(size_t)j * rst + d2];
        __syncthreads();
        sred[t] = v0 + v1 + v2; __syncthreads();
        for (int s = 128; s; s >>= 1) { if (t < s) sred[t] += sred[t + s]; __syncthreads(); }
        float mu = sred[0] / 768.f;
        __syncthreads();
        float a0 = v0 - mu, a1 = v1 - mu, a2 = v2 - mu;
        sred[t] = a0 * a0 + a1 * a1 + a2 * a2; __syncthreads();
        for (int s = 128; s; s >>= 1) { if (t < s) sred[t] += sred[t + s]; __syncthreads(); }
        float rs = rsqrtf(sred[0] / 768.f + 1e-5f);
        size_t base = (size_t)j * 768;
        float w0 = a0 * rs * gamma[d0] + beta[d0];
        float w1 = a1 * rs * gamma[d1] + beta[d1];
        float w2 = a2 * rs * gamma[d2] + beta[d2];
        if (outp) { outp[base + d0] = w0; outp[base + d1] = w1; outp[base + d2] = w2; }
        short hh;
        hh = f2bf(w0); ohi[base + d0] = hh; olo[base + d0] = f2bf(w0 - bf2f(hh));
        hh = f2bf(w1); ohi[base + d1] = hh; olo[base + d1] = f2bf(w1 - bf2f(hh));
        hh = f2bf(w2); ohi[base + d2] = hh; olo[base + d2] = f2bf(w2 - bf2f(hh));
    } else {
        accs[d0] = acc0; accs[d1] = acc1; accs[d2] = acc2;
        __syncthreads();
        float val = 0.f;
        if (t < CC)
            val = fmaxf((accs[t] + accs[t + CC] + accs[t + 2 * CC] + accs[t + 3 * CC]) * 0.25f
                        + gb[t], 0.f) + rres[(size_t)j * rst + t];
        __syncthreads();
        sred[t] = (t < CC) ? val : 0.f; __syncthreads();
        for (int s = 128; s; s >>= 1) { if (t < s) sred[t] += sred[t + s]; __syncthreads(); }
        float mu = sred[0] / (float)CC;
        __syncthreads();
        float a = val - mu;
        sred[t] = (t < CC) ? a * a : 0.f; __syncthreads();
        for (int s = 128; s; s >>= 1) { if (t < s) sred[t] += sred[t + s]; __syncthreads(); }
        float rs = rsqrtf(sred[0] / (float)CC + 1e-5f);
        float w = a * rs * ((t < CC) ? gamma[t] : 0.f) + ((t < CC) ? beta[t] : 0.f);
        if (t < CC) {
            size_t idx = (size_t)j * CC + t;
            if (outp) outp[idx] = w;
            if (ohi) {
                short hh = f2bf(w);
                ohi[idx] = hh; olo[idx] = f2bf(w - bf2f(hh));
            }
            accs[t] = w;
        }
        if (fco) {
            __syncthreads();
            if (t < 64) {
#pragma unroll
                for (int n = 0; n < 7; n++) {
                    float p = 0.f;
                    for (int d = t; d < CC; d += 64) p += accs[d] * fcw[d * 7 + n];
#pragma unroll
                    for (int off = 32; off; off >>= 1) p += __shfl_down(p, off);
                    if (t == 0) fco[(size_t)j * 7 + n] = p + fcb[n];
                }
            }
        }
    }
}

extern "C" void kernel_launch(void* const* d_in, const int* in_sizes, int n_in,
                              void* d_out, int out_size, void* d_ws, size_t ws_size,
                              hipStream_t stream)
{
    const float* x     = (const float*)d_in[0];
    const float* bn_g  = (const float*)d_in[1];
    const float* bn_b  = (const float*)d_in[2];
    const float* bn_rm = (const float*)d_in[3];
    const float* bn_rv = (const float*)d_in[4];
    const float* g_w[4]  = {(const float*)d_in[5], (const float*)d_in[9],
                            (const float*)d_in[13], (const float*)d_in[17]};
    const float* g_as[4] = {(const float*)d_in[6], (const float*)d_in[10],
                            (const float*)d_in[14], (const float*)d_in[18]};
    const float* g_ad[4] = {(const float*)d_in[7], (const float*)d_in[11],
                            (const float*)d_in[15], (const float*)d_in[19]};
    const float* g_b[4]  = {(const float*)d_in[8], (const float*)d_in[12],
                            (const float*)d_in[16], (const float*)d_in[20]};
    const float* res1_w = (const float*)d_in[21];
    const float* res1_b = (const float*)d_in[22];
    const float* res2_w = (const float*)d_in[23];
    const float* res2_b = (const float*)d_in[24];
    const float* ln_g[4] = {(const float*)d_in[25], (const float*)d_in[27],
                            (const float*)d_in[29], (const float*)d_in[31]};
    const float* ln_b[4] = {(const float*)d_in[26], (const float*)d_in[28],
                            (const float*)d_in[30], (const float*)d_in[32]};
    const float* fc_w = (const float*)d_in[33];
    const float* fc_b = (const float*)d_in[34];
    float* out = (float*)d_out;

    float* F = (float*)d_ws;
    float* ASIM = F; F += 16777216;  // sim chunk (2048 x 8192)
    float* R1   = F; F += 6291456;   // fp32 residual (768)
    float* H1   = F; F += 6291456;   // layer-1 LN out (residual for layer 2)
    float* R2   = F; F += 1572864;   // fp32 residual (192)
    float* H3   = F; F += 1572864;   // layer-3 LN out (residual for layer 4)
    float* ESB  = F; F += 262144;    // 4 x (es 32768 | ed 32768), pre-zeroed
    short* S = (short*)F;
    short* XNH = S; S += 6291456;
    short* XNL = S; S += 6291456;
    short* XAH = S; S += 6291456;
    short* XAL = S; S += 6291456;
    short* HBH = S; S += 6291456;    // bf16 h of current layer (8192 x 768)
    short* WT1H = S; S += 1179648;   // 1536 x 768
    short* WT1L = S; S += 1179648;
    short* WT2H = S; S += 589824;    // 768 x 768
    short* WT2L = S; S += 589824;
    short* WT3H = S; S += 737280;    // 960 x 768
    short* WT3L = S; S += 737280;
    short* WT4H = S; S += 147456;    // 768 x 192
    short* WT4L = S; S += 147456;
    int* I = (int*)S;
    int* NBR    = I; I += NN * KK;
    int* DEG    = I; I += NN;
    int* ROWPTR = I; I += NN + 8;
    int* CUR    = I; I += NN;
    int* MFL    = I; I += NN;
    int* CSR    = I; I += 131072;
    float* PV   = (float*)I; I += 147456;  // 2048*8*9
    int* PI     = I; I += 147456;
    float* ES[4], *ED[4];
    for (int l = 0; l < 4; l++) { ES[l] = ESB + l * 65536; ED[l] = ES[l] + 32768; }

    // 1. fused BN + rownorm + splits; zero es/ed + deg
    bnorm_kernel<<<NN, 256, 0, stream>>>(x, bn_g, bn_b, bn_rm, bn_rv,
                                         XAH, XAL, XNH, XNL);
    hipMemsetAsync(ESB, 0, 262144 * sizeof(float), stream);
    hipMemsetAsync(DEG, 0, NN * sizeof(int), stream);
    // 2. all weight transposes in one launch
    wtrans6<<<(4 * 589824 + 2 * 147456 + 255) / 256, 256, 0, stream>>>(
        res1_w, WT1H, WT1L,
        g_w[0], WT1H + 768 * 768, WT1L + 768 * 768,
        g_w[1], WT2H, WT2L,
        res2_w, WT3H, WT3L,
        g_w[2], WT3H + 192 * 768, WT3L + 192 * 768,
        g_w[3], WT4H, WT4L);
    // 3. sim + topk in 4 chunks of 2048 rows
    for (int ch = 0; ch < 4; ch++) {
        mfma_nt<<<dim3(NN / 128, 2048 / 128), 256, 0, stream>>>(
            XNH + (size_t)ch * 2048 * DD, XNL + (size_t)ch * 2048 * DD,
            XNH, XNL, nullptr, 0, ASIM, NN, nullptr, 0x7fffffff, 0,
            nullptr, nullptr, nullptr, nullptr, 0, 2048, DD, NN);
        topk1_kernel<<<4096, 256, 0, stream>>>(ASIM, PV, PI);
        topk2_kernel<<<512, 256, 0, stream>>>(PV, PI, NBR, ch * 2048);
    }
    // 4. edges -> CSR
    count_kernel<<<NN / 256, 256, 0, stream>>>(NBR, DEG, MFL);
    scan_kernel<<<1, 256, 0, stream>>>(DEG, ROWPTR, CUR);
    fill_kernel<<<NN / 256, 256, 0, stream>>>(NBR, MFL, CUR, CSR);
    // 5. layer 1: [r1(fp32) | h1(bf16)] = xb @ [res1_w | g1_w], es fused
    mfma_nt<<<dim3(12, NN / 128), 256, 0, stream>>>(XAH, XAL, WT1H, WT1L,
        res1_b, 768, R1, 768, HBH, 768, 768,
        g_as[0], g_ad[0], ES[0], ED[0], 768, NN, DD, 1536);
    agg_ln_kernel<<<NN, 256, 0, stream>>>(HBH, 768, ES[0], ED[0], ROWPTR, CSR,
        g_b[0], R1, 768, ln_g[0], ln_b[0], H1, XAH, XAL, HC, 1, nullptr, nullptr, nullptr);
    // 6. layer 2: all bf16 h, es fused
    mfma_nt<<<dim3(6, NN / 128), 256, 0, stream>>>(XAH, XAL, WT2H, WT2L,
        nullptr, 0, nullptr, 0, HBH, 0, 768,
        g_as[1], g_ad[1], ES[1], ED[1], 0, NN, HC, HC);
    agg_ln_kernel<<<NN, 256, 0, stream>>>(HBH, 768, ES[1], ED[1], ROWPTR, CSR,
        g_b[1], H1, 768, ln_g[1], ln_b[1], nullptr, XAH, XAL, HC, 1, nullptr, nullptr, nullptr);
    // 7. layer 3: [r2(fp32,192) | h3(bf16)] = h2 @ [res2_w | g3_w]
    mfma_nt<<<dim3(8, NN / 128), 256, 0, stream>>>(XAH, XAL, WT3H, WT3L,
        res2_b, 192, R2, 192, HBH, 192, 768,
        g_as[2], g_ad[2], ES[2], ED[2], 192, NN, HC, 960);
    agg_ln_kernel<<<NN, 256, 0, stream>>>(HBH, 768, ES[2], ED[2], ROWPTR, CSR,
        g_b[2], R2, 192, ln_g[2], ln_b[2], H3, XAH, XAL, CC, 0, nullptr, nullptr, nullptr);
    // 8. layer 4 (K=192) + fused final FC
    mfma_nt<<<dim3(6, NN / 128), 256, 0, stream>>>(XAH, XAL, WT4H, WT4L,
        nullptr, 0, nullptr, 0, HBH, 0, 768,
        g_as[3], g_ad[3], ES[3], ED[3], 0, NN, CC, HC);
    agg_ln_kernel<<<NN, 256, 0, stream>>>(HBH, 768, ES[3], ED[3], ROWPTR, CSR,
        g_b[3], H3, 192, ln_g[3], ln_b[3], nullptr, nullptr, nullptr, CC, 0, fc_w, fc_b, out);
}

// Round 10
// 1084.613 us; speedup vs baseline: 2.0187x; 1.1138x over previous
//
#include <hip/hip_runtime.h>
#include <hip/hip_bf16.h>

#define NN 8192
#define DD 768
#define HH 4
#define CC 192
#define KK 8
#define HC 768

typedef __attribute__((ext_vector_type(8))) short short8;
typedef __attribute__((ext_vector_type(4))) float floatx4;

static __device__ __forceinline__ short f2bf(float v) {
    unsigned u = __builtin_bit_cast(unsigned, v);
    u += 0x7fff + ((u >> 16) & 1);
    return (short)(u >> 16);
}
static __device__ __forceinline__ float bf2f(short s) {
    unsigned u = ((unsigned)(unsigned short)s) << 16;
    return __builtin_bit_cast(float, u);
}

// async global->LDS, 16B per lane, dest = wave-uniform base + lane*16
static __device__ __forceinline__ void gl16(const void* g, void* l) {
    __builtin_amdgcn_global_load_lds(
        (__attribute__((address_space(1))) void*)(void*)g,
        (__attribute__((address_space(3))) void*)l, 16, 0, 0);
}

// -------------------- fused BN + rownorm + bf16 hi/lo splits --------------
__global__ __launch_bounds__(256) void bnorm_kernel(const float* __restrict__ x,
    const float* __restrict__ g, const float* __restrict__ b,
    const float* __restrict__ rm, const float* __restrict__ rv,
    short* __restrict__ xbh, short* __restrict__ xbl,
    short* __restrict__ xnh, short* __restrict__ xnl)
{
    int i = blockIdx.x, t = threadIdx.x;
    __shared__ float red[256];
    float v[3];
    float ss = 0.f;
#pragma unroll
    for (int q = 0; q < 3; q++) {
        int d = t + q * 256;
        float xv = x[(size_t)i * DD + d];
        float vv = (xv - rm[d]) * rsqrtf(rv[d] + 1e-5f) * g[d] + b[d];
        v[q] = vv; ss += vv * vv;
    }
    red[t] = ss; __syncthreads();
    for (int s = 128; s; s >>= 1) { if (t < s) red[t] += red[t + s]; __syncthreads(); }
    float inv = 1.0f / (sqrtf(red[0]) + 1e-8f);
#pragma unroll
    for (int q = 0; q < 3; q++) {
        int d = t + q * 256;
        size_t idx = (size_t)i * DD + d;
        float vv = v[q];
        short h = f2bf(vv);
        xbh[idx] = h; xbl[idx] = f2bf(vv - bf2f(h));
        float nv = vv * inv;
        short nh = f2bf(nv);
        xnh[idx] = nh; xnl[idx] = f2bf(nv - bf2f(nh));
    }
}

// --------- all 6 weight transposes (hi/lo, W[KxP] -> Wt[PxK]) in one ------
__global__ __launch_bounds__(256) void wtrans6(
    const float* w0, short* o0h, short* o0l,   // res1 768x768
    const float* w1, short* o1h, short* o1l,   // g1   768x768
    const float* w2, short* o2h, short* o2l,   // g2   768x768
    const float* w3, short* o3h, short* o3l,   // res2 768x192
    const float* w4, short* o4h, short* o4l,   // g3   768x768
    const float* w5, short* o5h, short* o5l)   // g4   192x768
{
    int idx = blockIdx.x * 256 + threadIdx.x;
    const float* w; short* oh; short* ol; int K, P; int r;
    if (idx < 589824)            { w = w0; oh = o0h; ol = o0l; K = 768; P = 768; r = idx; }
    else if (idx < 2 * 589824)   { w = w1; oh = o1h; ol = o1l; K = 768; P = 768; r = idx - 589824; }
    else if (idx < 3 * 589824)   { w = w2; oh = o2h; ol = o2l; K = 768; P = 768; r = idx - 2 * 589824; }
    else if (idx < 3 * 589824 + 147456) { w = w3; oh = o3h; ol = o3l; K = 768; P = 192; r = idx - 3 * 589824; }
    else if (idx < 4 * 589824 + 147456) { w = w4; oh = o4h; ol = o4l; K = 768; P = 768; r = idx - 3 * 589824 - 147456; }
    else if (idx < 4 * 589824 + 2 * 147456) { w = w5; oh = o5h; ol = o5l; K = 192; P = 768; r = idx - 4 * 589824 - 147456; }
    else return;
    int p = r / K, k = r % K;
    float v = w[(size_t)k * P + p];
    short h = f2bf(v);
    oh[r] = h;
    ol[r] = f2bf(v - bf2f(h));
}

// -------- symmetric sim GEMM: tile + mirrored(transposed) tile write ------
// Panels are 4096x4096 fp32. diag=1: 1D triangle grid (bi<=bj), Cba==Cab.
// diag=0: grid (32,32), straight -> Cab, mirror -> Cba.
__global__ __launch_bounds__(256) void mfma_sym(
    const short* __restrict__ Xh, const short* __restrict__ Xl,
    int rowa, int rowb, int diag,
    float* __restrict__ Cab, float* __restrict__ Cba)
{
    __shared__ __attribute__((aligned(16))) float fsm[64 * 129];  // 33 KB
    short* sAh = (short*)fsm;
    short* sAl = (short*)fsm + 4096;
    short* sBh = (short*)fsm + 8192;
    short* sBl = (short*)fsm + 12288;
    int t = threadIdx.x;
    int wave = t >> 6, lane = t & 63;
    int wm = wave & 1, wn = wave >> 1;
    int bi, bj;
    if (diag) {
        int L = blockIdx.x;
        int j = (int)((sqrtf(8.f * (float)L + 1.f) - 1.f) * 0.5f);
        while (j * (j + 1) / 2 > L) j--;
        while ((j + 1) * (j + 2) / 2 <= L) j++;
        bi = L - j * (j + 1) / 2; bj = j;
    } else { bi = blockIdx.y; bj = blockIdx.x; }
    int i0 = bi * 128, j0 = bj * 128;
    int mrow = lane & 15, quad = lane >> 4;

    int srow = lane >> 2;
    int kg   = (lane & 3) ^ ((lane >> 3) & 3);
    int koff = kg * 8;
    int c0 = wave * 2, c1 = c0 + 1;
    int ar0 = rowa + i0 + c0 * 16 + srow, ar1 = rowa + i0 + c1 * 16 + srow;
    int br0 = rowb + j0 + c0 * 16 + srow, br1 = rowb + j0 + c1 * 16 + srow;
    const short* pAh0 = Xh + (size_t)ar0 * DD + koff;
    const short* pAh1 = Xh + (size_t)ar1 * DD + koff;
    const short* pAl0 = Xl + (size_t)ar0 * DD + koff;
    const short* pAl1 = Xl + (size_t)ar1 * DD + koff;
    const short* pBh0 = Xh + (size_t)br0 * DD + koff;
    const short* pBh1 = Xh + (size_t)br1 * DD + koff;
    const short* pBl0 = Xl + (size_t)br0 * DD + koff;
    const short* pBl1 = Xl + (size_t)br1 * DD + koff;
    short* dA0 = sAh + c0 * 512; short* dA1 = sAh + c1 * 512;
    short* dAl0 = sAl + c0 * 512; short* dAl1 = sAl + c1 * 512;
    short* dB0 = sBh + c0 * 512; short* dB1 = sBh + c1 * 512;
    short* dBl0 = sBl + c0 * 512; short* dBl1 = sBl + c1 * 512;

    floatx4 acc[4][4];
#pragma unroll
    for (int a = 0; a < 4; a++)
#pragma unroll
        for (int b = 0; b < 4; b++) acc[a][b] = (floatx4){0.f, 0.f, 0.f, 0.f};

    int aoff[4], boff[4];
#pragma unroll
    for (int mt = 0; mt < 4; mt++) {
        int r = wm * 64 + mt * 16 + mrow;
        aoff[mt] = r * 32 + (quad ^ ((r >> 1) & 3)) * 8;
    }
#pragma unroll
    for (int nt = 0; nt < 4; nt++) {
        int r = wn * 64 + nt * 16 + mrow;
        boff[nt] = r * 32 + (quad ^ ((r >> 1) & 3)) * 8;
    }

    for (int k0 = 0; k0 < DD; k0 += 32) {
        gl16(pAh0 + k0, dA0);  gl16(pAh1 + k0, dA1);
        gl16(pAl0 + k0, dAl0); gl16(pAl1 + k0, dAl1);
        gl16(pBh0 + k0, dB0);  gl16(pBh1 + k0, dB1);
        gl16(pBl0 + k0, dBl0); gl16(pBl1 + k0, dBl1);
        __syncthreads();

        short8 ah[4], al[4], bh[4], bl[4];
#pragma unroll
        for (int mt = 0; mt < 4; mt++) {
            ah[mt] = *(const short8*)(sAh + aoff[mt]);
            al[mt] = *(const short8*)(sAl + aoff[mt]);
        }
#pragma unroll
        for (int nt = 0; nt < 4; nt++) {
            bh[nt] = *(const short8*)(sBh + boff[nt]);
            bl[nt] = *(const short8*)(sBl + boff[nt]);
        }
#pragma unroll
        for (int mt = 0; mt < 4; mt++)
#pragma unroll
            for (int nt = 0; nt < 4; nt++) {
                acc[mt][nt] = __builtin_amdgcn_mfma_f32_16x16x32_bf16(
                    ah[mt], bh[nt], acc[mt][nt], 0, 0, 0);
                acc[mt][nt] = __builtin_amdgcn_mfma_f32_16x16x32_bf16(
                    ah[mt], bl[nt], acc[mt][nt], 0, 0, 0);
                acc[mt][nt] = __builtin_amdgcn_mfma_f32_16x16x32_bf16(
                    al[mt], bh[nt], acc[mt][nt], 0, 0, 0);
            }
        __syncthreads();
    }

    // straight write
#pragma unroll
    for (int mt = 0; mt < 4; mt++)
#pragma unroll
        for (int nt = 0; nt < 4; nt++) {
            int col = j0 + wn * 64 + nt * 16 + mrow;
#pragma unroll
            for (int r = 0; r < 4; r++) {
                int row = i0 + wm * 64 + mt * 16 + quad * 4 + r;
                Cab[(size_t)row * 4096 + col] = acc[mt][nt][r];
            }
        }

    // mirrored write via LDS transpose (stride 129: ~2-way banks = free)
    if (!diag || bi != bj) {
        float* Cm = Cba;
        for (int half = 0; half < 2; half++) {
            __syncthreads();
            if (wn == half) {
#pragma unroll
                for (int mt = 0; mt < 4; mt++)
#pragma unroll
                    for (int nt = 0; nt < 4; nt++)
#pragma unroll
                        for (int r = 0; r < 4; r++) {
                            int c = nt * 16 + mrow;                      // local col in half
                            int rr = wm * 64 + mt * 16 + quad * 4 + r;   // row 0..127
                            fsm[c * 129 + rr] = acc[mt][nt][r];
                        }
            }
            __syncthreads();
            for (int it = 0; it < 32; it++) {
                int idx = it * 256 + t;
                int lr = idx >> 7, lc = idx & 127;
                Cm[(size_t)(j0 + half * 64 + lr) * 4096 + i0 + lc] = fsm[lr * 129 + lc];
            }
        }
    }
}

// ---------------- split-bf16 MFMA GEMM for layers, C = A @ B^T ------------
// cols [0,bfoff): fp32 -> C (stride Cstride, +bias for col<biasN)
// cols [bfoff,P): bf16 -> Cbf at col-bfoff (stride bfstride)
// optional fused es/ed partial dots (a_s/a_d [4][192], h region starts hoff)
__global__ __launch_bounds__(256) void mfma_nt(
    const short* __restrict__ Ahi, const short* __restrict__ Alo,
    const short* __restrict__ Bhi, const short* __restrict__ Blo,
    const float* __restrict__ bias, int biasN,
    float* __restrict__ C, int Cstride,
    short* __restrict__ Cbf, int bfoff, int bfstride,
    const float* __restrict__ a_s, const float* __restrict__ a_d,
    float* __restrict__ es, float* __restrict__ ed, int hoff,
    int M, int K, int P)
{
    __shared__ __attribute__((aligned(16))) short sAh[128 * 32];
    __shared__ __attribute__((aligned(16))) short sAl[128 * 32];
    __shared__ __attribute__((aligned(16))) short sBh[128 * 32];
    __shared__ __attribute__((aligned(16))) short sBl[128 * 32];
    int t = threadIdx.x;
    int wave = t >> 6, lane = t & 63;
    int wm = wave & 1, wn = wave >> 1;
    int i0 = blockIdx.y * 128, j0 = blockIdx.x * 128;
    int mrow = lane & 15, quad = lane >> 4;

    int srow = lane >> 2;
    int kg   = (lane & 3) ^ ((lane >> 3) & 3);
    int koff = kg * 8;
    int c0 = wave * 2, c1 = c0 + 1;
    int ar0 = i0 + c0 * 16 + srow, ar1 = i0 + c1 * 16 + srow;
    int br0 = j0 + c0 * 16 + srow, br1 = j0 + c1 * 16 + srow;
    if (br0 > P - 1) br0 = P - 1;
    if (br1 > P - 1) br1 = P - 1;
    const short* pAh0 = Ahi + (size_t)ar0 * K + koff;
    const short* pAh1 = Ahi + (size_t)ar1 * K + koff;
    const short* pAl0 = Alo + (size_t)ar0 * K + koff;
    const short* pAl1 = Alo + (size_t)ar1 * K + koff;
    const short* pBh0 = Bhi + (size_t)br0 * K + koff;
    const short* pBh1 = Bhi + (size_t)br1 * K + koff;
    const short* pBl0 = Blo + (size_t)br0 * K + koff;
    const short* pBl1 = Blo + (size_t)br1 * K + koff;
    short* dA0 = sAh + c0 * 512; short* dA1 = sAh + c1 * 512;
    short* dAl0 = sAl + c0 * 512; short* dAl1 = sAl + c1 * 512;
    short* dB0 = sBh + c0 * 512; short* dB1 = sBh + c1 * 512;
    short* dBl0 = sBl + c0 * 512; short* dBl1 = sBl + c1 * 512;

    floatx4 acc[4][4];
#pragma unroll
    for (int a = 0; a < 4; a++)
#pragma unroll
        for (int b = 0; b < 4; b++) acc[a][b] = (floatx4){0.f, 0.f, 0.f, 0.f};

    int aoff[4], boff[4];
#pragma unroll
    for (int mt = 0; mt < 4; mt++) {
        int r = wm * 64 + mt * 16 + mrow;
        aoff[mt] = r * 32 + (quad ^ ((r >> 1) & 3)) * 8;
    }
#pragma unroll
    for (int nt = 0; nt < 4; nt++) {
        int r = wn * 64 + nt * 16 + mrow;
        boff[nt] = r * 32 + (quad ^ ((r >> 1) & 3)) * 8;
    }

    for (int k0 = 0; k0 < K; k0 += 32) {
        gl16(pAh0 + k0, dA0);  gl16(pAh1 + k0, dA1);
        gl16(pAl0 + k0, dAl0); gl16(pAl1 + k0, dAl1);
        gl16(pBh0 + k0, dB0);  gl16(pBh1 + k0, dB1);
        gl16(pBl0 + k0, dBl0); gl16(pBl1 + k0, dBl1);
        __syncthreads();

        short8 ah[4], al[4], bh[4], bl[4];
#pragma unroll
        for (int mt = 0; mt < 4; mt++) {
            ah[mt] = *(const short8*)(sAh + aoff[mt]);
            al[mt] = *(const short8*)(sAl + aoff[mt]);
        }
#pragma unroll
        for (int nt = 0; nt < 4; nt++) {
            bh[nt] = *(const short8*)(sBh + boff[nt]);
            bl[nt] = *(const short8*)(sBl + boff[nt]);
        }
#pragma unroll
        for (int mt = 0; mt < 4; mt++)
#pragma unroll
            for (int nt = 0; nt < 4; nt++) {
                acc[mt][nt] = __builtin_amdgcn_mfma_f32_16x16x32_bf16(
                    ah[mt], bh[nt], acc[mt][nt], 0, 0, 0);
                acc[mt][nt] = __builtin_amdgcn_mfma_f32_16x16x32_bf16(
                    ah[mt], bl[nt], acc[mt][nt], 0, 0, 0);
                acc[mt][nt] = __builtin_amdgcn_mfma_f32_16x16x32_bf16(
                    al[mt], bh[nt], acc[mt][nt], 0, 0, 0);
            }
        __syncthreads();
    }

#pragma unroll
    for (int mt = 0; mt < 4; mt++)
#pragma unroll
        for (int nt = 0; nt < 4; nt++) {
            int col = j0 + wn * 64 + nt * 16 + mrow;
            if (col < P) {
                if (col < bfoff) {
                    float bb = (bias && col < biasN) ? bias[col] : 0.f;
#pragma unroll
                    for (int r = 0; r < 4; r++) {
                        int row = i0 + wm * 64 + mt * 16 + quad * 4 + r;
                        C[(size_t)row * Cstride + col] = acc[mt][nt][r] + bb;
                    }
                } else {
#pragma unroll
                    for (int r = 0; r < 4; r++) {
                        int row = i0 + wm * 64 + mt * 16 + quad * 4 + r;
                        Cbf[(size_t)row * bfstride + col - bfoff] = f2bf(acc[mt][nt][r]);
                    }
                }
            }
        }

    // fused es/ed partial dots: wave's 64-col window lies in one head
    if (a_s) {
        int base = j0 + wn * 64;
        if (base >= hoff && base + 64 <= P) {
            int head = (base - hoff) / CC;
            int cb = (base - hoff) % CC;
#pragma unroll
            for (int mt = 0; mt < 4; mt++) {
                float ps[4] = {0.f, 0.f, 0.f, 0.f};
                float pd[4] = {0.f, 0.f, 0.f, 0.f};
#pragma unroll
                for (int nt = 0; nt < 4; nt++) {
                    int c = cb + nt * 16 + mrow;
                    float as_ = a_s[head * CC + c];
                    float ad_ = a_d[head * CC + c];
#pragma unroll
                    for (int r = 0; r < 4; r++) {
                        ps[r] += acc[mt][nt][r] * as_;
                        pd[r] += acc[mt][nt][r] * ad_;
                    }
                }
#pragma unroll
                for (int off = 1; off < 16; off <<= 1)
#pragma unroll
                    for (int r = 0; r < 4; r++) {
                        ps[r] += __shfl_xor(ps[r], off);
                        pd[r] += __shfl_xor(pd[r], off);
                    }
                if (mrow == 0) {
#pragma unroll
                    for (int r = 0; r < 4; r++) {
                        int row = i0 + wm * 64 + mt * 16 + quad * 4 + r;
                        atomicAdd(&es[row * 4 + head], ps[r]);
                        atomicAdd(&ed[row * 4 + head], pd[r]);
                    }
                }
            }
        }
    }
}

// -------------------------------------------------------------- top-k
__device__ __forceinline__ bool tk_try(float* v, int* id, float xv, int xi)
{
    if (xv > v[8] || (xv == v[8] && xi < id[8])) {
        v[8] = xv; id[8] = xi;
#pragma unroll
        for (int p = 8; p > 0; p--) {
            if (v[p] > v[p - 1] || (v[p] == v[p - 1] && id[p] < id[p - 1])) {
                float tv = v[p]; v[p] = v[p - 1]; v[p - 1] = tv;
                int ti2 = id[p]; id[p] = id[p - 1]; id[p - 1] = ti2;
            } else break;
        }
        return true;
    }
    return false;
}

// stage 1 (panel): one wave per (row, 1024-col seg) of a 4096x4096 panel.
// Writes sorted seg top-9 to pv/pi[((rowbase+row)*8 + segbase+seg)*9 + rank].
__global__ __launch_bounds__(256) void topk1p_kernel(const float* __restrict__ sim,
    float* __restrict__ pv, int* __restrict__ pi,
    int rowbase, int segbase, int colbase)
{
    int wave = threadIdx.x >> 6, lane = threadIdx.x & 63;
    int task = blockIdx.x * 4 + wave;
    int row = task >> 2, seg = task & 3;
    const float4* p4 = (const float4*)(sim + (size_t)row * 4096 + seg * 1024);

    float4 f0 = p4[lane], f1 = p4[lane + 64], f2 = p4[lane + 128], f3 = p4[lane + 192];
    float v[9]; int id[9];
#pragma unroll
    for (int q = 0; q < 9; q++) { v[q] = -3e38f; id[q] = 0x7fffffff; }
    int jb = colbase + seg * 1024 + lane * 4;
#pragma unroll
    for (int g = 0; g < 4; g++) {
        float4 f = g == 0 ? f0 : (g == 1 ? f1 : (g == 2 ? f2 : f3));
        float gm = fmaxf(fmaxf(f.x, f.y), fmaxf(f.z, f.w));
        if (gm >= v[8]) {
            int j = jb + g * 256;
            tk_try(v, id, f.x, j);
            tk_try(v, id, f.y, j + 1);
            tk_try(v, id, f.z, j + 2);
            tk_try(v, id, f.w, j + 3);
        }
    }
    float wv = -3e38f; int wi = 0x7fffffff;
#pragma unroll
    for (int r = 0; r < 9; r++) {
        float bv = v[0]; int bi = id[0];
#pragma unroll
        for (int off = 1; off < 64; off <<= 1) {
            float ov = __shfl_xor(bv, off);
            int oi = __shfl_xor(bi, off);
            if (ov > bv || (ov == bv && oi < bi)) { bv = ov; bi = oi; }
        }
        if (id[0] == bi) {
#pragma unroll
            for (int q = 0; q < 8; q++) { v[q] = v[q + 1]; id[q] = id[q + 1]; }
            v[8] = -3e38f; id[8] = 0x7fffffff;
        }
        if (lane == r) { wv = bv; wi = bi; }
    }
    if (lane < 9) {
        size_t o = ((size_t)(rowbase + row) * 8 + segbase + seg) * 9 + lane;
        pv[o] = wv; pi[o] = wi;
    }
}

// stage 2: one wave per row merges 8 sorted 9-lists (72 candidates).
__global__ __launch_bounds__(256) void topk2_kernel(const float* __restrict__ pv,
    const int* __restrict__ pi, int* __restrict__ nbr, int r0)
{
    int wave = threadIdx.x >> 6, lane = threadIdx.x & 63;
    int row = blockIdx.x * 4 + wave;
    size_t base = (size_t)row * 72;
    float v[2]; int id[2];
    v[0] = -3e38f; id[0] = 0x7fffffff;
    v[1] = -3e38f; id[1] = 0x7fffffff;
    if (lane < 72) { v[0] = pv[base + lane]; id[0] = pi[base + lane]; }
    if (lane < 8)  { v[1] = pv[base + 64 + lane]; id[1] = pi[base + 64 + lane]; }
    if (v[1] > v[0] || (v[1] == v[0] && id[1] < id[0])) {
        float tv = v[0]; v[0] = v[1]; v[1] = tv;
        int ti = id[0]; id[0] = id[1]; id[1] = ti;
    }
    int myi = 0;
#pragma unroll
    for (int r = 0; r < 9; r++) {
        float bv = v[0]; int bi = id[0];
#pragma unroll
        for (int off = 1; off < 64; off <<= 1) {
            float ov = __shfl_xor(bv, off);
            int oi = __shfl_xor(bi, off);
            if (ov > bv || (ov == bv && oi < bi)) { bv = ov; bi = oi; }
        }
        if (id[0] == bi) {
            v[0] = v[1]; id[0] = id[1];
            v[1] = -3e38f; id[1] = 0x7fffffff;
        }
        if (r >= 1 && lane == r - 1) myi = bi;
    }
    if (lane < KK) nbr[(size_t)(r0 + row) * KK + lane] = myi;
}

// ------------------------------------------------------ edge building
__global__ __launch_bounds__(256) void count_kernel(const int* __restrict__ nbr,
                                                    int* __restrict__ deg, int* __restrict__ mfl)
{
    int i = blockIdx.x * 256 + threadIdx.x;
    if (i >= NN) return;
    atomicAdd(&deg[i], 1); // self loop
    int mm = 0;
#pragma unroll
    for (int k = 0; k < KK; k++) {
        int j = nbr[i * KK + k];
        atomicAdd(&deg[j], 1);
        if (j == i + 1) mm = 1;
    }
    if (i < NN - 1) {
        mfl[i] = !mm;
        if (!mm) { atomicAdd(&deg[i + 1], 1); atomicAdd(&deg[i], 1); }
    }
}

__global__ __launch_bounds__(256) void scan_kernel(const int* __restrict__ deg,
                                                   int* __restrict__ rowptr, int* __restrict__ cur)
{
    __shared__ int sums[256];
    int t = threadIdx.x;
    int loc[32];
    int base = t * 32;
    int s = 0;
#pragma unroll
    for (int q = 0; q < 32; q++) { loc[q] = s; s += deg[base + q]; }
    sums[t] = s; __syncthreads();
    for (int off = 1; off < 256; off <<= 1) {
        int v = (t >= off) ? sums[t - off] : 0;
        __syncthreads();
        sums[t] += v;
        __syncthreads();
    }
    int myoff = (t == 0) ? 0 : sums[t - 1];
#pragma unroll
    for (int q = 0; q < 32; q++) { int rp = myoff + loc[q]; rowptr[base + q] = rp; cur[base + q] = rp; }
    if (t == 255) rowptr[NN] = sums[255];
}

__global__ __launch_bounds__(256) void fill_kernel(const int* __restrict__ nbr,
    const int* __restrict__ mfl, int* __restrict__ cur, int* __restrict__ csr)
{
    int i = blockIdx.x * 256 + threadIdx.x;
    if (i >= NN) return;
    int pos = atomicAdd(&cur[i], 1); csr[pos] = i; // self
#pragma unroll
    for (int k = 0; k < KK; k++) {
        int j = nbr[i * KK + k];
        pos = atomicAdd(&cur[j], 1); csr[pos] = i;
    }
    if (i < NN - 1 && mfl[i]) {
        pos = atomicAdd(&cur[i + 1], 1); csr[pos] = i;
        pos = atomicAdd(&cur[i], 1); csr[pos] = i + 1;
    }
}

// ------- softmax-attention aggregate (bf16 h) + relu + residual + LN ------
__global__ __launch_bounds__(256) void agg_ln_kernel(const short* __restrict__ h, int hst,
    const float* __restrict__ es, const float* __restrict__ ed,
    const int* __restrict__ rowptr, const int* __restrict__ csr,
    const float* __restrict__ gb, const float* __restrict__ rres, int rst,
    const float* __restrict__ gamma, const float* __restrict__ beta,
    float* __restrict__ outp, short* __restrict__ ohi, short* __restrict__ olo,
    int Dm, int concat,
    const float* __restrict__ fcw, const float* __restrict__ fcb,
    float* __restrict__ fco)
{
    int j = blockIdx.x;
    int t = threadIdx.x;
    int lane = t & 63, wave = t >> 6;
    __shared__ int ssrc[256];
    __shared__ float sal[256 * 4];
    __shared__ float sred[1024];
    __shared__ float accs[768];
    int p0 = rowptr[j], p1 = rowptr[j + 1];
    int cnt = p1 - p0;
    float edj[4];
#pragma unroll
    for (int hd = 0; hd < 4; hd++) edj[hd] = ed[j * 4 + hd];

    float acc0 = 0.f, acc1 = 0.f, acc2 = 0.f;
    int d0 = t, d1 = t + 256, d2 = t + 512;
    int h0 = d0 / CC, h1_ = d1 / CC, h2_ = d2 / CC;

    if (cnt <= 256) {
        float e[4];
        if (t < cnt) {
            int s = csr[p0 + t];
            ssrc[t] = s;
#pragma unroll
            for (int hd = 0; hd < 4; hd++) {
                float ee = es[s * 4 + hd] + edj[hd];
                e[hd] = ee > 0.f ? ee : 0.2f * ee;
            }
        } else {
#pragma unroll
            for (int hd = 0; hd < 4; hd++) e[hd] = -1e30f;
        }
        float mh[4];
#pragma unroll
        for (int hd = 0; hd < 4; hd++) {
            float rv = e[hd];
#pragma unroll
            for (int off = 32; off; off >>= 1) rv = fmaxf(rv, __shfl_down(rv, off));
            if (lane == 0) sred[wave * 4 + hd] = rv;
        }
        __syncthreads();
#pragma unroll
        for (int hd = 0; hd < 4; hd++)
            mh[hd] = fmaxf(fmaxf(sred[hd], sred[4 + hd]), fmaxf(sred[8 + hd], sred[12 + hd]));
        __syncthreads();
        float ex[4];
#pragma unroll
        for (int hd = 0; hd < 4; hd++) {
            ex[hd] = (t < cnt) ? expf(e[hd] - mh[hd]) : 0.f;
            float rv = ex[hd];
#pragma unroll
            for (int off = 32; off; off >>= 1) rv += __shfl_down(rv, off);
            if (lane == 0) sred[wave * 4 + hd] = rv;
        }
        __syncthreads();
#pragma unroll
        for (int hd = 0; hd < 4; hd++) {
            float dh = sred[hd] + sred[4 + hd] + sred[8 + hd] + sred[12 + hd] + 1e-16f;
            if (t < cnt) sal[t * 4 + hd] = ex[hd] / dh;
        }
        __syncthreads();
        for (int e2 = 0; e2 < cnt; e2++) {
            const short* hs = h + (size_t)ssrc[e2] * hst;
            acc0 += sal[e2 * 4 + h0] * bf2f(hs[d0]);
            acc1 += sal[e2 * 4 + h1_] * bf2f(hs[d1]);
            acc2 += sal[e2 * 4 + h2_] * bf2f(hs[d2]);
        }
    } else {
        float mh[4] = {-1e30f, -1e30f, -1e30f, -1e30f};
        for (int p = p0 + t; p < p1; p += 256) {
            int s = csr[p];
#pragma unroll
            for (int hd = 0; hd < 4; hd++) {
                float e = es[s * 4 + hd] + edj[hd];
                e = e > 0.f ? e : 0.2f * e;
                mh[hd] = fmaxf(mh[hd], e);
            }
        }
#pragma unroll
        for (int hd = 0; hd < 4; hd++) sred[hd * 256 + t] = mh[hd];
        __syncthreads();
        for (int s2 = 128; s2; s2 >>= 1) {
            if (t < s2)
#pragma unroll
                for (int hd = 0; hd < 4; hd++)
                    sred[hd * 256 + t] = fmaxf(sred[hd * 256 + t], sred[hd * 256 + t + s2]);
            __syncthreads();
        }
#pragma unroll
        for (int hd = 0; hd < 4; hd++) mh[hd] = sred[hd * 256];
        __syncthreads();
        float sh[4] = {0.f, 0.f, 0.f, 0.f};
        for (int p = p0 + t; p < p1; p += 256) {
            int s = csr[p];
#pragma unroll
            for (int hd = 0; hd < 4; hd++) {
                float e = es[s * 4 + hd] + edj[hd];
                e = e > 0.f ? e : 0.2f * e;
                sh[hd] += expf(e - mh[hd]);
            }
        }
#pragma unroll
        for (int hd = 0; hd < 4; hd++) sred[hd * 256 + t] = sh[hd];
        __syncthreads();
        for (int s2 = 128; s2; s2 >>= 1) {
            if (t < s2)
#pragma unroll
                for (int hd = 0; hd < 4; hd++)
                    sred[hd * 256 + t] += sred[hd * 256 + t + s2];
            __syncthreads();
        }
        float dh[4];
#pragma unroll
        for (int hd = 0; hd < 4; hd++) dh[hd] = sred[hd * 256] + 1e-16f;
        __syncthreads();
        for (int p = p0; p < p1; p += 64) {
            int cn = min(64, p1 - p);
            if (t < cn) {
                int s = csr[p + t];
                ssrc[t] = s;
#pragma unroll
                for (int hd = 0; hd < 4; hd++) {
                    float e = es[s * 4 + hd] + edj[hd];
                    e = e > 0.f ? e : 0.2f * e;
                    sal[t * 4 + hd] = expf(e - mh[hd]) / dh[hd];
                }
            }
            __syncthreads();
            for (int e2 = 0; e2 < cn; e2++) {
                const short* hs = h + (size_t)ssrc[e2] * hst;
                acc0 += sal[e2 * 4 + h0] * bf2f(hs[d0]);
                acc1 += sal[e2 * 4 + h1_] * bf2f(hs[d1]);
                acc2 += sal[e2 * 4 + h2_] * bf2f(hs[d2]);
            }
            __syncthreads();
        }
    }

    if (concat) {
        float v0 = fmaxf(acc0 + gb[d0], 0.f) + rres[(size_t)j * rst + d0];
        float v1 = fmaxf(acc1 + gb[d1], 0.f) + rres[(size_t)j * rst + d1];
        float v2 = fmaxf(acc2 + gb[d2], 0.f) + rres[(size_t)j * rst + d2];
        __syncthreads();
        sred[t] = v0 + v1 + v2; __syncthreads();
        for (int s = 128; s; s >>= 1) { if (t < s) sred[t] += sred[t + s]; __syncthreads(); }
        float mu = sred[0] / 768.f;
        __syncthreads();
        float a0 = v0 - mu, a1 = v1 - mu, a2 = v2 - mu;
        sred[t] = a0 * a0 + a1 * a1 + a2 * a2; __syncthreads();
        for (int s = 128; s; s >>= 1) { if (t < s) sred[t] += sred[t + s]; __syncthreads(); }
        float rs = rsqrtf(sred[0] / 768.f + 1e-5f);
        size_t base = (size_t)j * 768;
        float w0 = a0 * rs * gamma[d0] + beta[d0];
        float w1 = a1 * rs * gamma[d1] + beta[d1];
        float w2 = a2 * rs * gamma[d2] + beta[d2];
        if (outp) { outp[base + d0] = w0; outp[base + d1] = w1; outp[base + d2] = w2; }
        short hh;
        hh = f2bf(w0); ohi[base + d0] = hh; olo[base + d0] = f2bf(w0 - bf2f(hh));
        hh = f2bf(w1); ohi[base + d1] = hh; olo[base + d1] = f2bf(w1 - bf2f(hh));
        hh = f2bf(w2); ohi[base + d2] = hh; olo[base + d2] = f2bf(w2 - bf2f(hh));
    } else {
        accs[d0] = acc0; accs[d1] = acc1; accs[d2] = acc2;
        __syncthreads();
        float val = 0.f;
        if (t < CC)
            val = fmaxf((accs[t] + accs[t + CC] + accs[t + 2 * CC] + accs[t + 3 * CC]) * 0.25f
                        + gb[t], 0.f) + rres[(size_t)j * rst + t];
        __syncthreads();
        sred[t] = (t < CC) ? val : 0.f; __syncthreads();
        for (int s = 128; s; s >>= 1) { if (t < s) sred[t] += sred[t + s]; __syncthreads(); }
        float mu = sred[0] / (float)CC;
        __syncthreads();
        float a = val - mu;
        sred[t] = (t < CC) ? a * a : 0.f; __syncthreads();
        for (int s = 128; s; s >>= 1) { if (t < s) sred[t] += sred[t + s]; __syncthreads(); }
        float rs = rsqrtf(sred[0] / (float)CC + 1e-5f);
        float w = a * rs * ((t < CC) ? gamma[t] : 0.f) + ((t < CC) ? beta[t] : 0.f);
        if (t < CC) {
            size_t idx = (size_t)j * CC + t;
            if (outp) outp[idx] = w;
            if (ohi) {
                short hh = f2bf(w);
                ohi[idx] = hh; olo[idx] = f2bf(w - bf2f(hh));
            }
            accs[t] = w;
        }
        if (fco) {
            __syncthreads();
            if (t < 64) {
#pragma unroll
                for (int n = 0; n < 7; n++) {
                    float p = 0.f;
                    for (int d = t; d < CC; d += 64) p += accs[d] * fcw[d * 7 + n];
#pragma unroll
                    for (int off = 32; off; off >>= 1) p += __shfl_down(p, off);
                    if (t == 0) fco[(size_t)j * 7 + n] = p + fcb[n];
                }
            }
        }
    }
}

extern "C" void kernel_launch(void* const* d_in, const int* in_sizes, int n_in,
                              void* d_out, int out_size, void* d_ws, size_t ws_size,
                              hipStream_t stream)
{
    const float* x     = (const float*)d_in[0];
    const float* bn_g  = (const float*)d_in[1];
    const float* bn_b  = (const float*)d_in[2];
    const float* bn_rm = (const float*)d_in[3];
    const float* bn_rv = (const float*)d_in[4];
    const float* g_w[4]  = {(const float*)d_in[5], (const float*)d_in[9],
                            (const float*)d_in[13], (const float*)d_in[17]};
    const float* g_as[4] = {(const float*)d_in[6], (const float*)d_in[10],
                            (const float*)d_in[14], (const float*)d_in[18]};
    const float* g_ad[4] = {(const float*)d_in[7], (const float*)d_in[11],
                            (const float*)d_in[15], (const float*)d_in[19]};
    const float* g_b[4]  = {(const float*)d_in[8], (const float*)d_in[12],
                            (const float*)d_in[16], (const float*)d_in[20]};
    const float* res1_w = (const float*)d_in[21];
    const float* res1_b = (const float*)d_in[22];
    const float* res2_w = (const float*)d_in[23];
    const float* res2_b = (const float*)d_in[24];
    const float* ln_g[4] = {(const float*)d_in[25], (const float*)d_in[27],
                            (const float*)d_in[29], (const float*)d_in[31]};
    const float* ln_b[4] = {(const float*)d_in[26], (const float*)d_in[28],
                            (const float*)d_in[30], (const float*)d_in[32]};
    const float* fc_w = (const float*)d_in[33];
    const float* fc_b = (const float*)d_in[34];
    float* out = (float*)d_out;

    float* F = (float*)d_ws;
    float* SAB  = F; F += 16777216;  // 4096x4096 panel (also S00)
    // UNION region (64 MB): SBA during sim; R1/H1/R2/H3/ESB afterwards.
    float* UNI  = F; F += 16777216;
    float* SBA = UNI;                        // 4096x4096 panel (also S11)
    float* R1  = UNI;                        // fp32 residual (768)   6291456
    float* H1  = R1 + 6291456;               // layer-1 LN out        6291456
    float* R2  = H1 + 6291456;               // fp32 residual (192)   1572864
    float* H3  = R2 + 1572864;               // layer-3 LN out        1572864
    float* ESB = H3 + 1572864;               // 4 x (es|ed) 262144 (zeroed post-sim)
    short* S = (short*)F;
    short* XNH = S; S += 6291456;
    short* XNL = S; S += 6291456;
    short* XAH = S; S += 6291456;
    short* XAL = S; S += 6291456;
    short* HBH = S; S += 6291456;    // bf16 h of current layer (8192 x 768)
    short* WT1H = S; S += 1179648;   // 1536 x 768
    short* WT1L = S; S += 1179648;
    short* WT2H = S; S += 589824;    // 768 x 768
    short* WT2L = S; S += 589824;
    short* WT3H = S; S += 737280;    // 960 x 768
    short* WT3L = S; S += 737280;
    short* WT4H = S; S += 147456;    // 768 x 192
    short* WT4L = S; S += 147456;
    int* I = (int*)S;
    int* NBR    = I; I += NN * KK;
    int* DEG    = I; I += NN;
    int* ROWPTR = I; I += NN + 8;
    int* CUR    = I; I += NN;
    int* MFL    = I; I += NN;
    int* CSR    = I; I += 131072;
    float* PV   = (float*)I; I += 589824;  // 8192 x 8 segs x 9
    int* PI     = I; I += 589824;
    float* ES[4], *ED[4];
    for (int l = 0; l < 4; l++) { ES[l] = ESB + l * 65536; ED[l] = ES[l] + 32768; }

    // 1. fused BN + rownorm + splits; zero deg
    bnorm_kernel<<<NN, 256, 0, stream>>>(x, bn_g, bn_b, bn_rm, bn_rv,
                                         XAH, XAL, XNH, XNL);
    hipMemsetAsync(DEG, 0, NN * sizeof(int), stream);
    // 2. all weight transposes in one launch
    wtrans6<<<(4 * 589824 + 2 * 147456 + 255) / 256, 256, 0, stream>>>(
        res1_w, WT1H, WT1L,
        g_w[0], WT1H + 768 * 768, WT1L + 768 * 768,
        g_w[1], WT2H, WT2L,
        res2_w, WT3H, WT3L,
        g_w[2], WT3H + 192 * 768, WT3L + 192 * 768,
        g_w[3], WT4H, WT4L);
    // 3. symmetric sim: off-diag pair + 2 diagonal triangles; panel top-9s
    mfma_sym<<<dim3(32, 32), 256, 0, stream>>>(XNH, XNL, 0, 4096, 0, SAB, SBA);
    topk1p_kernel<<<4096, 256, 0, stream>>>(SAB, PV, PI, 0, 4, 4096);
    topk1p_kernel<<<4096, 256, 0, stream>>>(SBA, PV, PI, 4096, 0, 0);
    mfma_sym<<<528, 256, 0, stream>>>(XNH, XNL, 0, 0, 1, SAB, SAB);
    topk1p_kernel<<<4096, 256, 0, stream>>>(SAB, PV, PI, 0, 0, 0);
    mfma_sym<<<528, 256, 0, stream>>>(XNH, XNL, 4096, 4096, 1, SBA, SBA);
    topk1p_kernel<<<4096, 256, 0, stream>>>(SBA, PV, PI, 4096, 4, 4096);
    topk2_kernel<<<NN / 4, 256, 0, stream>>>(PV, PI, NBR, 0);
    // 4. edges -> CSR; zero es/ed now (ESB aliases SBA, sim is done)
    count_kernel<<<NN / 256, 256, 0, stream>>>(NBR, DEG, MFL);
    scan_kernel<<<1, 256, 0, stream>>>(DEG, ROWPTR, CUR);
    fill_kernel<<<NN / 256, 256, 0, stream>>>(NBR, MFL, CUR, CSR);
    hipMemsetAsync(ESB, 0, 262144 * sizeof(float), stream);
    // 5. layer 1: [r1(fp32) | h1(bf16)] = xb @ [res1_w | g1_w], es fused
    mfma_nt<<<dim3(12, NN / 128), 256, 0, stream>>>(XAH, XAL, WT1H, WT1L,
        res1_b, 768, R1, 768, HBH, 768, 768,
        g_as[0], g_ad[0], ES[0], ED[0], 768, NN, DD, 1536);
    agg_ln_kernel<<<NN, 256, 0, stream>>>(HBH, 768, ES[0], ED[0], ROWPTR, CSR,
        g_b[0], R1, 768, ln_g[0], ln_b[0], H1, XAH, XAL, HC, 1, nullptr, nullptr, nullptr);
    // 6. layer 2: all bf16 h, es fused
    mfma_nt<<<dim3(6, NN / 128), 256, 0, stream>>>(XAH, XAL, WT2H, WT2L,
        nullptr, 0, nullptr, 0, HBH, 0, 768,
        g_as[1], g_ad[1], ES[1], ED[1], 0, NN, HC, HC);
    agg_ln_kernel<<<NN, 256, 0, stream>>>(HBH, 768, ES[1], ED[1], ROWPTR, CSR,
        g_b[1], H1, 768, ln_g[1], ln_b[1], nullptr, XAH, XAL, HC, 1, nullptr, nullptr, nullptr);
    // 7. layer 3: [r2(fp32,192) | h3(bf16)] = h2 @ [res2_w | g3_w]
    mfma_nt<<<dim3(8, NN / 128), 256, 0, stream>>>(XAH, XAL, WT3H, WT3L,
        res2_b, 192, R2, 192, HBH, 192, 768,
        g_as[2], g_ad[2], ES[2], ED[2], 192, NN, HC, 960);
    agg_ln_kernel<<<NN, 256, 0, stream>>>(HBH, 768, ES[2], ED[2], ROWPTR, CSR,
        g_b[2], R2, 192, ln_g[2], ln_b[2], H3, XAH, XAL, CC, 0, nullptr, nullptr, nullptr);
    // 8. layer 4 (K=192) + fused final FC
    mfma_nt<<<dim3(6, NN / 128), 256, 0, stream>>>(XAH, XAL, WT4H, WT4L,
        nullptr, 0, nullptr, 0, HBH, 0, 768,
        g_as[3], g_ad[3], ES[3], ED[3], 0, NN, CC, HC);
    agg_ln_kernel<<<NN, 256, 0, stream>>>(HBH, 768, ES[3], ED[3], ROWPTR, CSR,
        g_b[3], H3, 192, ln_g[3], ln_b[3], nullptr, nullptr, nullptr, CC, 0, fc_w, fc_b, out);
}

// Round 11
// 1081.652 us; speedup vs baseline: 2.0242x; 1.0027x over previous
//
#include <hip/hip_runtime.h>
#include <hip/hip_bf16.h>

#define NN 8192
#define DD 768
#define HH 4
#define CC 192
#define KK 8
#define HC 768

typedef __attribute__((ext_vector_type(8))) short short8;
typedef __attribute__((ext_vector_type(4))) float floatx4;

static __device__ __forceinline__ short f2bf(float v) {
    unsigned u = __builtin_bit_cast(unsigned, v);
    u += 0x7fff + ((u >> 16) & 1);
    return (short)(u >> 16);
}
static __device__ __forceinline__ float bf2f(short s) {
    unsigned u = ((unsigned)(unsigned short)s) << 16;
    return __builtin_bit_cast(float, u);
}

// async global->LDS, 16B per lane, dest = wave-uniform base + lane*16
static __device__ __forceinline__ void gl16(const void* g, void* l) {
    __builtin_amdgcn_global_load_lds(
        (__attribute__((address_space(1))) void*)(void*)g,
        (__attribute__((address_space(3))) void*)l, 16, 0, 0);
}

// ---------- fused BN + rownorm + splits (xb hi/lo, xn bf16 + fp32) --------
__global__ __launch_bounds__(256) void bnorm_kernel(const float* __restrict__ x,
    const float* __restrict__ g, const float* __restrict__ b,
    const float* __restrict__ rm, const float* __restrict__ rv,
    short* __restrict__ xbh, short* __restrict__ xbl,
    short* __restrict__ xnh, float* __restrict__ xnf)
{
    int i = blockIdx.x, t = threadIdx.x;
    __shared__ float red[256];
    float v[3];
    float ss = 0.f;
#pragma unroll
    for (int q = 0; q < 3; q++) {
        int d = t + q * 256;
        float xv = x[(size_t)i * DD + d];
        float vv = (xv - rm[d]) * rsqrtf(rv[d] + 1e-5f) * g[d] + b[d];
        v[q] = vv; ss += vv * vv;
    }
    red[t] = ss; __syncthreads();
    for (int s = 128; s; s >>= 1) { if (t < s) red[t] += red[t + s]; __syncthreads(); }
    float inv = 1.0f / (sqrtf(red[0]) + 1e-8f);
#pragma unroll
    for (int q = 0; q < 3; q++) {
        int d = t + q * 256;
        size_t idx = (size_t)i * DD + d;
        float vv = v[q];
        short h = f2bf(vv);
        xbh[idx] = h; xbl[idx] = f2bf(vv - bf2f(h));
        float nv = vv * inv;
        xnf[idx] = nv;
        xnh[idx] = f2bf(nv);
    }
}

// --------- all 6 weight transposes (hi/lo, W[KxP] -> Wt[PxK]) in one ------
__global__ __launch_bounds__(256) void wtrans6(
    const float* w0, short* o0h, short* o0l,
    const float* w1, short* o1h, short* o1l,
    const float* w2, short* o2h, short* o2l,
    const float* w3, short* o3h, short* o3l,
    const float* w4, short* o4h, short* o4l,
    const float* w5, short* o5h, short* o5l)
{
    int idx = blockIdx.x * 256 + threadIdx.x;
    const float* w; short* oh; short* ol; int K, P; int r;
    if (idx < 589824)            { w = w0; oh = o0h; ol = o0l; K = 768; P = 768; r = idx; }
    else if (idx < 2 * 589824)   { w = w1; oh = o1h; ol = o1l; K = 768; P = 768; r = idx - 589824; }
    else if (idx < 3 * 589824)   { w = w2; oh = o2h; ol = o2l; K = 768; P = 768; r = idx - 2 * 589824; }
    else if (idx < 3 * 589824 + 147456) { w = w3; oh = o3h; ol = o3l; K = 768; P = 192; r = idx - 3 * 589824; }
    else if (idx < 4 * 589824 + 147456) { w = w4; oh = o4h; ol = o4l; K = 768; P = 768; r = idx - 3 * 589824 - 147456; }
    else if (idx < 4 * 589824 + 2 * 147456) { w = w5; oh = o5h; ol = o5l; K = 192; P = 768; r = idx - 4 * 589824 - 147456; }
    else return;
    int p = r / K, k = r % K;
    float v = w[(size_t)k * P + p];
    short h = f2bf(v);
    oh[r] = h;
    ol[r] = f2bf(v - bf2f(h));
}

// ------ symmetric sim GEMM, 1-term bf16, bf16-out panels (4096x4096) ------
// mode 0: off-diag pair, grid(32,32): straight -> P0, mirror -> P1.
// mode 1: both diag triangles merged, grid 1056: L<528 -> P0, else P1.
__global__ __launch_bounds__(256) void mfma_sym(
    const short* __restrict__ Xh, int mode,
    short* __restrict__ P0, short* __restrict__ P1)
{
    __shared__ __attribute__((aligned(16))) short smem[8704];
    short* sAh = smem;          // 4096
    short* sBh = smem + 4096;   // 4096
    int t = threadIdx.x;
    int wave = t >> 6, lane = t & 63;
    int wm = wave & 1, wn = wave >> 1;
    int bi, bj, rowa, rowb; short *Cab, *Cba;
    if (mode == 0) {
        bi = blockIdx.y; bj = blockIdx.x; rowa = 0; rowb = 4096;
        Cab = P0; Cba = P1;
    } else {
        int L = blockIdx.x;
        int which = (L >= 528) ? 1 : 0; L -= which * 528;
        int j = (int)((sqrtf(8.f * (float)L + 1.f) - 1.f) * 0.5f);
        while (j * (j + 1) / 2 > L) j--;
        while ((j + 1) * (j + 2) / 2 <= L) j++;
        bi = L - j * (j + 1) / 2; bj = j;
        rowa = rowb = which ? 4096 : 0;
        Cab = Cba = which ? P1 : P0;
    }
    int i0 = bi * 128, j0 = bj * 128;
    int mrow = lane & 15, quad = lane >> 4;

    int srow = lane >> 2;
    int kg   = (lane & 3) ^ ((lane >> 3) & 3);
    int koff = kg * 8;
    int c0 = wave * 2, c1 = c0 + 1;
    const short* pA0 = Xh + (size_t)(rowa + i0 + c0 * 16 + srow) * DD + koff;
    const short* pA1 = Xh + (size_t)(rowa + i0 + c1 * 16 + srow) * DD + koff;
    const short* pB0 = Xh + (size_t)(rowb + j0 + c0 * 16 + srow) * DD + koff;
    const short* pB1 = Xh + (size_t)(rowb + j0 + c1 * 16 + srow) * DD + koff;
    short* dA0 = sAh + c0 * 512; short* dA1 = sAh + c1 * 512;
    short* dB0 = sBh + c0 * 512; short* dB1 = sBh + c1 * 512;

    floatx4 acc[4][4];
#pragma unroll
    for (int a = 0; a < 4; a++)
#pragma unroll
        for (int b = 0; b < 4; b++) acc[a][b] = (floatx4){0.f, 0.f, 0.f, 0.f};

    int aoff[4], boff[4];
#pragma unroll
    for (int mt = 0; mt < 4; mt++) {
        int r = wm * 64 + mt * 16 + mrow;
        aoff[mt] = r * 32 + (quad ^ ((r >> 1) & 3)) * 8;
    }
#pragma unroll
    for (int nt = 0; nt < 4; nt++) {
        int r = wn * 64 + nt * 16 + mrow;
        boff[nt] = r * 32 + (quad ^ ((r >> 1) & 3)) * 8;
    }

    for (int k0 = 0; k0 < DD; k0 += 32) {
        gl16(pA0 + k0, dA0); gl16(pA1 + k0, dA1);
        gl16(pB0 + k0, dB0); gl16(pB1 + k0, dB1);
        __syncthreads();
        short8 ah[4], bh[4];
#pragma unroll
        for (int mt = 0; mt < 4; mt++) ah[mt] = *(const short8*)(sAh + aoff[mt]);
#pragma unroll
        for (int nt = 0; nt < 4; nt++) bh[nt] = *(const short8*)(sBh + boff[nt]);
#pragma unroll
        for (int mt = 0; mt < 4; mt++)
#pragma unroll
            for (int nt = 0; nt < 4; nt++)
                acc[mt][nt] = __builtin_amdgcn_mfma_f32_16x16x32_bf16(
                    ah[mt], bh[nt], acc[mt][nt], 0, 0, 0);
        __syncthreads();
    }

    // epilogue: straight write via LDS staging (vectorized short8 rows)
    short* st = smem;   // 64 x 136 shorts
    for (int half = 0; half < 2; half++) {
        __syncthreads();
        if (wm == half) {
#pragma unroll
            for (int mt = 0; mt < 4; mt++)
#pragma unroll
                for (int nt = 0; nt < 4; nt++)
#pragma unroll
                    for (int r = 0; r < 4; r++)
                        st[(mt * 16 + quad * 4 + r) * 136 + wn * 64 + nt * 16 + mrow]
                            = f2bf(acc[mt][nt][r]);
        }
        __syncthreads();
#pragma unroll
        for (int it = 0; it < 4; it++) {
            int idx = it * 256 + t;
            int lr = idx >> 4, lc = (idx & 15) * 8;
            *(short8*)&Cab[(size_t)(i0 + half * 64 + lr) * 4096 + j0 + lc]
                = *(const short8*)&st[lr * 136 + lc];
        }
    }
    // mirrored (transposed) write
    if (mode == 0 || bi != bj) {
        for (int half = 0; half < 2; half++) {
            __syncthreads();
            if (wn == half) {
#pragma unroll
                for (int mt = 0; mt < 4; mt++)
#pragma unroll
                    for (int nt = 0; nt < 4; nt++)
#pragma unroll
                        for (int r = 0; r < 4; r++)
                            st[(nt * 16 + mrow) * 136 + wm * 64 + mt * 16 + quad * 4 + r]
                                = f2bf(acc[mt][nt][r]);
            }
            __syncthreads();
#pragma unroll
            for (int it = 0; it < 4; it++) {
                int idx = it * 256 + t;
                int lr = idx >> 4, lc = (idx & 15) * 8;
                *(short8*)&Cba[(size_t)(j0 + half * 64 + lr) * 4096 + i0 + lc]
                    = *(const short8*)&st[lr * 136 + lc];
            }
        }
    }
}

// -------------------------------------------------------------- top-k
__device__ __forceinline__ bool tk_try(float* v, int* id, float xv, int xi)
{
    if (xv > v[8] || (xv == v[8] && xi < id[8])) {
        v[8] = xv; id[8] = xi;
#pragma unroll
        for (int p = 8; p > 0; p--) {
            if (v[p] > v[p - 1] || (v[p] == v[p - 1] && id[p] < id[p - 1])) {
                float tv = v[p]; v[p] = v[p - 1]; v[p - 1] = tv;
                int ti2 = id[p]; id[p] = id[p - 1]; id[p - 1] = ti2;
            } else break;
        }
        return true;
    }
    return false;
}

// stage 1: per (row, 1024-col seg) of both bf16 panels -> sorted seg top-9.
// phase 0: A=(rows0-4095, segs4-7, cols4096+), B=(rows4096+, segs0-3, cols0+)
// phase 1: A=(rows0-4095, segs0-3, cols0+),   B=(rows4096+, segs4-7, cols4096+)
__global__ __launch_bounds__(256) void topk1b_kernel(
    const short* __restrict__ simA, const short* __restrict__ simB,
    float* __restrict__ pv, int* __restrict__ pi, int phase)
{
    int wave = threadIdx.x >> 6, lane = threadIdx.x & 63;
    int gtask = blockIdx.x * 4 + wave;
    int which = (gtask >= 16384) ? 1 : 0;
    int task = gtask - which * 16384;
    const short* sim = which ? simB : simA;
    int rowbase = which ? 4096 : 0;
    int segbase, colbase;
    if (phase == 0) { segbase = which ? 0 : 4; colbase = which ? 0 : 4096; }
    else            { segbase = which ? 4 : 0; colbase = which ? 4096 : 0; }
    int row = task >> 2, seg = task & 3;
    const short8* p8 = (const short8*)(sim + (size_t)row * 4096 + seg * 1024);
    short8 s0 = p8[lane], s1 = p8[lane + 64];
    float v[9]; int id[9];
#pragma unroll
    for (int q = 0; q < 9; q++) { v[q] = -3e38f; id[q] = 0x7fffffff; }
    int jb = colbase + seg * 1024 + lane * 8;
    float f0[8], f1[8];
#pragma unroll
    for (int q = 0; q < 8; q++) { f0[q] = bf2f(s0[q]); f1[q] = bf2f(s1[q]); }
    float g0 = f0[0], g1 = f1[0];
#pragma unroll
    for (int q = 1; q < 8; q++) { g0 = fmaxf(g0, f0[q]); g1 = fmaxf(g1, f1[q]); }
    if (g0 >= v[8]) {
#pragma unroll
        for (int q = 0; q < 8; q++) tk_try(v, id, f0[q], jb + q);
    }
    if (g1 >= v[8]) {
#pragma unroll
        for (int q = 0; q < 8; q++) tk_try(v, id, f1[q], jb + 512 + q);
    }
    float wv = -3e38f; int wi = 0x7fffffff;
#pragma unroll
    for (int r = 0; r < 9; r++) {
        float bv = v[0]; int bi = id[0];
#pragma unroll
        for (int off = 1; off < 64; off <<= 1) {
            float ov = __shfl_xor(bv, off);
            int oi = __shfl_xor(bi, off);
            if (ov > bv || (ov == bv && oi < bi)) { bv = ov; bi = oi; }
        }
        if (id[0] == bi) {
#pragma unroll
            for (int q = 0; q < 8; q++) { v[q] = v[q + 1]; id[q] = id[q + 1]; }
            v[8] = -3e38f; id[8] = 0x7fffffff;
        }
        if (lane == r) { wv = bv; wi = bi; }
    }
    if (lane < 9) {
        size_t o = ((size_t)(rowbase + row) * 8 + segbase + seg) * 9 + lane;
        pv[o] = wv; pi[o] = wi;
    }
}

// stage 2: merge 72 bf16 candidates -> top-24, rescore in fp32, exact top-9.
__global__ __launch_bounds__(256) void rescore_kernel(
    const float* __restrict__ xnf,
    const float* __restrict__ pv, const int* __restrict__ pi,
    int* __restrict__ nbr)
{
    int row = blockIdx.x, t = threadIdx.x;
    int wave = t >> 6, lane = t & 63;
    __shared__ float own[768];
    __shared__ float cv[72]; __shared__ int ci[72];
    __shared__ int seli[24];
    __shared__ float rv[24]; __shared__ int ri[24];
    for (int d = t; d < 768; d += 256) own[d] = xnf[(size_t)row * 768 + d];
    if (t < 72) { cv[t] = pv[(size_t)row * 72 + t]; ci[t] = pi[(size_t)row * 72 + t]; }
    __syncthreads();
    if (wave == 0) {
        float v[2]; int id[2];
        v[0] = (lane < 72) ? cv[lane] : -3e38f;
        id[0] = (lane < 72) ? ci[lane] : 0x7fffffff;
        v[1] = (lane < 8) ? cv[64 + lane] : -3e38f;
        id[1] = (lane < 8) ? ci[64 + lane] : 0x7fffffff;
        if (v[1] > v[0] || (v[1] == v[0] && id[1] < id[0])) {
            float tv = v[0]; v[0] = v[1]; v[1] = tv;
            int ti = id[0]; id[0] = id[1]; id[1] = ti;
        }
#pragma unroll
        for (int r = 0; r < 24; r++) {
            float bv = v[0]; int bi = id[0];
#pragma unroll
            for (int off = 1; off < 64; off <<= 1) {
                float ov = __shfl_xor(bv, off);
                int oi = __shfl_xor(bi, off);
                if (ov > bv || (ov == bv && oi < bi)) { bv = ov; bi = oi; }
            }
            if (id[0] == bi) {
                v[0] = v[1]; id[0] = id[1];
                v[1] = -3e38f; id[1] = 0x7fffffff;
            }
            if (lane == r) seli[r] = bi;
        }
    }
    __syncthreads();
    float ow[12];
#pragma unroll
    for (int q = 0; q < 12; q++) ow[q] = own[q * 64 + lane];
    for (int k = 0; k < 6; k++) {
        int c = wave * 6 + k;
        int src = seli[c];
        const float* cr = xnf + (size_t)src * 768;
        float s = 0.f;
#pragma unroll
        for (int q = 0; q < 12; q++) s += ow[q] * cr[q * 64 + lane];
#pragma unroll
        for (int off = 32; off; off >>= 1) s += __shfl_xor(s, off);
        if (lane == 0) { rv[c] = s; ri[c] = src; }
    }
    __syncthreads();
    if (wave == 0) {
        float v0 = (lane < 24) ? rv[lane] : -3e38f;
        int i0_ = (lane < 24) ? ri[lane] : 0x7fffffff;
        int myi = 0;
#pragma unroll
        for (int r = 0; r < 9; r++) {
            float bv = v0; int bi = i0_;
#pragma unroll
            for (int off = 1; off < 64; off <<= 1) {
                float ov = __shfl_xor(bv, off);
                int oi = __shfl_xor(bi, off);
                if (ov > bv || (ov == bv && oi < bi)) { bv = ov; bi = oi; }
            }
            if (i0_ == bi) { v0 = -3e38f; i0_ = 0x7fffffff; }
            if (r >= 1 && lane == r - 1) myi = bi;   // rank 0 = self
        }
        if (lane < KK) nbr[(size_t)row * KK + lane] = myi;
    }
}

// ------------------------------------------------------ edge building
__global__ __launch_bounds__(256) void count_kernel(const int* __restrict__ nbr,
                                                    int* __restrict__ deg, int* __restrict__ mfl)
{
    int i = blockIdx.x * 256 + threadIdx.x;
    if (i >= NN) return;
    atomicAdd(&deg[i], 1); // self loop
    int mm = 0;
#pragma unroll
    for (int k = 0; k < KK; k++) {
        int j = nbr[i * KK + k];
        atomicAdd(&deg[j], 1);
        if (j == i + 1) mm = 1;
    }
    if (i < NN - 1) {
        mfl[i] = !mm;
        if (!mm) { atomicAdd(&deg[i + 1], 1); atomicAdd(&deg[i], 1); }
    }
}

__global__ __launch_bounds__(256) void scan_kernel(const int* __restrict__ deg,
                                                   int* __restrict__ rowptr, int* __restrict__ cur)
{
    __shared__ int sums[256];
    int t = threadIdx.x;
    int loc[32];
    int base = t * 32;
    int s = 0;
#pragma unroll
    for (int q = 0; q < 32; q++) { loc[q] = s; s += deg[base + q]; }
    sums[t] = s; __syncthreads();
    for (int off = 1; off < 256; off <<= 1) {
        int v = (t >= off) ? sums[t - off] : 0;
        __syncthreads();
        sums[t] += v;
        __syncthreads();
    }
    int myoff = (t == 0) ? 0 : sums[t - 1];
#pragma unroll
    for (int q = 0; q < 32; q++) { int rp = myoff + loc[q]; rowptr[base + q] = rp; cur[base + q] = rp; }
    if (t == 255) rowptr[NN] = sums[255];
}

__global__ __launch_bounds__(256) void fill_kernel(const int* __restrict__ nbr,
    const int* __restrict__ mfl, int* __restrict__ cur, int* __restrict__ csr)
{
    int i = blockIdx.x * 256 + threadIdx.x;
    if (i >= NN) return;
    int pos = atomicAdd(&cur[i], 1); csr[pos] = i; // self
#pragma unroll
    for (int k = 0; k < KK; k++) {
        int j = nbr[i * KK + k];
        pos = atomicAdd(&cur[j], 1); csr[pos] = i;
    }
    if (i < NN - 1 && mfl[i]) {
        pos = atomicAdd(&cur[i + 1], 1); csr[pos] = i;
        pos = atomicAdd(&cur[i], 1); csr[pos] = i + 1;
    }
}

// ---------------- split-bf16 MFMA GEMM for layers, C = A @ B^T ------------
__global__ __launch_bounds__(256) void mfma_nt(
    const short* __restrict__ Ahi, const short* __restrict__ Alo,
    const short* __restrict__ Bhi, const short* __restrict__ Blo,
    const float* __restrict__ bias, int biasN,
    float* __restrict__ C, int Cstride,
    short* __restrict__ Cbf, int bfoff, int bfstride,
    const float* __restrict__ a_s, const float* __restrict__ a_d,
    float* __restrict__ es, float* __restrict__ ed, int hoff,
    int M, int K, int P)
{
    __shared__ __attribute__((aligned(16))) short sAh[128 * 32];
    __shared__ __attribute__((aligned(16))) short sAl[128 * 32];
    __shared__ __attribute__((aligned(16))) short sBh[128 * 32];
    __shared__ __attribute__((aligned(16))) short sBl[128 * 32];
    int t = threadIdx.x;
    int wave = t >> 6, lane = t & 63;
    int wm = wave & 1, wn = wave >> 1;
    int i0 = blockIdx.y * 128, j0 = blockIdx.x * 128;
    int mrow = lane & 15, quad = lane >> 4;

    int srow = lane >> 2;
    int kg   = (lane & 3) ^ ((lane >> 3) & 3);
    int koff = kg * 8;
    int c0 = wave * 2, c1 = c0 + 1;
    int ar0 = i0 + c0 * 16 + srow, ar1 = i0 + c1 * 16 + srow;
    int br0 = j0 + c0 * 16 + srow, br1 = j0 + c1 * 16 + srow;
    if (br0 > P - 1) br0 = P - 1;
    if (br1 > P - 1) br1 = P - 1;
    const short* pAh0 = Ahi + (size_t)ar0 * K + koff;
    const short* pAh1 = Ahi + (size_t)ar1 * K + koff;
    const short* pAl0 = Alo + (size_t)ar0 * K + koff;
    const short* pAl1 = Alo + (size_t)ar1 * K + koff;
    const short* pBh0 = Bhi + (size_t)br0 * K + koff;
    const short* pBh1 = Bhi + (size_t)br1 * K + koff;
    const short* pBl0 = Blo + (size_t)br0 * K + koff;
    const short* pBl1 = Blo + (size_t)br1 * K + koff;
    short* dA0 = sAh + c0 * 512; short* dA1 = sAh + c1 * 512;
    short* dAl0 = sAl + c0 * 512; short* dAl1 = sAl + c1 * 512;
    short* dB0 = sBh + c0 * 512; short* dB1 = sBh + c1 * 512;
    short* dBl0 = sBl + c0 * 512; short* dBl1 = sBl + c1 * 512;

    floatx4 acc[4][4];
#pragma unroll
    for (int a = 0; a < 4; a++)
#pragma unroll
        for (int b = 0; b < 4; b++) acc[a][b] = (floatx4){0.f, 0.f, 0.f, 0.f};

    int aoff[4], boff[4];
#pragma unroll
    for (int mt = 0; mt < 4; mt++) {
        int r = wm * 64 + mt * 16 + mrow;
        aoff[mt] = r * 32 + (quad ^ ((r >> 1) & 3)) * 8;
    }
#pragma unroll
    for (int nt = 0; nt < 4; nt++) {
        int r = wn * 64 + nt * 16 + mrow;
        boff[nt] = r * 32 + (quad ^ ((r >> 1) & 3)) * 8;
    }

    for (int k0 = 0; k0 < K; k0 += 32) {
        gl16(pAh0 + k0, dA0);  gl16(pAh1 + k0, dA1);
        gl16(pAl0 + k0, dAl0); gl16(pAl1 + k0, dAl1);
        gl16(pBh0 + k0, dB0);  gl16(pBh1 + k0, dB1);
        gl16(pBl0 + k0, dBl0); gl16(pBl1 + k0, dBl1);
        __syncthreads();

        short8 ah[4], al[4], bh[4], bl[4];
#pragma unroll
        for (int mt = 0; mt < 4; mt++) {
            ah[mt] = *(const short8*)(sAh + aoff[mt]);
            al[mt] = *(const short8*)(sAl + aoff[mt]);
        }
#pragma unroll
        for (int nt = 0; nt < 4; nt++) {
            bh[nt] = *(const short8*)(sBh + boff[nt]);
            bl[nt] = *(const short8*)(sBl + boff[nt]);
        }
#pragma unroll
        for (int mt = 0; mt < 4; mt++)
#pragma unroll
            for (int nt = 0; nt < 4; nt++) {
                acc[mt][nt] = __builtin_amdgcn_mfma_f32_16x16x32_bf16(
                    ah[mt], bh[nt], acc[mt][nt], 0, 0, 0);
                acc[mt][nt] = __builtin_amdgcn_mfma_f32_16x16x32_bf16(
                    ah[mt], bl[nt], acc[mt][nt], 0, 0, 0);
                acc[mt][nt] = __builtin_amdgcn_mfma_f32_16x16x32_bf16(
                    al[mt], bh[nt], acc[mt][nt], 0, 0, 0);
            }
        __syncthreads();
    }

#pragma unroll
    for (int mt = 0; mt < 4; mt++)
#pragma unroll
        for (int nt = 0; nt < 4; nt++) {
            int col = j0 + wn * 64 + nt * 16 + mrow;
            if (col < P) {
                if (col < bfoff) {
                    float bb = (bias && col < biasN) ? bias[col] : 0.f;
#pragma unroll
                    for (int r = 0; r < 4; r++) {
                        int row = i0 + wm * 64 + mt * 16 + quad * 4 + r;
                        C[(size_t)row * Cstride + col] = acc[mt][nt][r] + bb;
                    }
                } else {
#pragma unroll
                    for (int r = 0; r < 4; r++) {
                        int row = i0 + wm * 64 + mt * 16 + quad * 4 + r;
                        Cbf[(size_t)row * bfstride + col - bfoff] = f2bf(acc[mt][nt][r]);
                    }
                }
            }
        }

    if (a_s) {
        int base = j0 + wn * 64;
        if (base >= hoff && base + 64 <= P) {
            int head = (base - hoff) / CC;
            int cb = (base - hoff) % CC;
#pragma unroll
            for (int mt = 0; mt < 4; mt++) {
                float ps[4] = {0.f, 0.f, 0.f, 0.f};
                float pd[4] = {0.f, 0.f, 0.f, 0.f};
#pragma unroll
                for (int nt = 0; nt < 4; nt++) {
                    int c = cb + nt * 16 + mrow;
                    float as_ = a_s[head * CC + c];
                    float ad_ = a_d[head * CC + c];
#pragma unroll
                    for (int r = 0; r < 4; r++) {
                        ps[r] += acc[mt][nt][r] * as_;
                        pd[r] += acc[mt][nt][r] * ad_;
                    }
                }
#pragma unroll
                for (int off = 1; off < 16; off <<= 1)
#pragma unroll
                    for (int r = 0; r < 4; r++) {
                        ps[r] += __shfl_xor(ps[r], off);
                        pd[r] += __shfl_xor(pd[r], off);
                    }
                if (mrow == 0) {
#pragma unroll
                    for (int r = 0; r < 4; r++) {
                        int row = i0 + wm * 64 + mt * 16 + quad * 4 + r;
                        atomicAdd(&es[row * 4 + head], ps[r]);
                        atomicAdd(&ed[row * 4 + head], pd[r]);
                    }
                }
            }
        }
    }
}

// ------- softmax-attention aggregate (bf16 h) + relu + residual + LN ------
__global__ __launch_bounds__(256) void agg_ln_kernel(const short* __restrict__ h, int hst,
    const float* __restrict__ es, const float* __restrict__ ed,
    const int* __restrict__ rowptr, const int* __restrict__ csr,
    const float* __restrict__ gb, const float* __restrict__ rres, int rst,
    const float* __restrict__ gamma, const float* __restrict__ beta,
    float* __restrict__ outp, short* __restrict__ ohi, short* __restrict__ olo,
    int Dm, int concat,
    const float* __restrict__ fcw, const float* __restrict__ fcb,
    float* __restrict__ fco)
{
    int j = blockIdx.x;
    int t = threadIdx.x;
    int lane = t & 63, wave = t >> 6;
    __shared__ int ssrc[256];
    __shared__ float sal[256 * 4];
    __shared__ float sred[1024];
    __shared__ float accs[768];
    int p0 = rowptr[j], p1 = rowptr[j + 1];
    int cnt = p1 - p0;
    float edj[4];
#pragma unroll
    for (int hd = 0; hd < 4; hd++) edj[hd] = ed[j * 4 + hd];

    float acc0 = 0.f, acc1 = 0.f, acc2 = 0.f;
    int d0 = t, d1 = t + 256, d2 = t + 512;
    int h0 = d0 / CC, h1_ = d1 / CC, h2_ = d2 / CC;

    if (cnt <= 256) {
        float e[4];
        if (t < cnt) {
            int s = csr[p0 + t];
            ssrc[t] = s;
#pragma unroll
            for (int hd = 0; hd < 4; hd++) {
                float ee = es[s * 4 + hd] + edj[hd];
                e[hd] = ee > 0.f ? ee : 0.2f * ee;
            }
        } else {
#pragma unroll
            for (int hd = 0; hd < 4; hd++) e[hd] = -1e30f;
        }
        float mh[4];
#pragma unroll
        for (int hd = 0; hd < 4; hd++) {
            float rv = e[hd];
#pragma unroll
            for (int off = 32; off; off >>= 1) rv = fmaxf(rv, __shfl_down(rv, off));
            if (lane == 0) sred[wave * 4 + hd] = rv;
        }
        __syncthreads();
#pragma unroll
        for (int hd = 0; hd < 4; hd++)
            mh[hd] = fmaxf(fmaxf(sred[hd], sred[4 + hd]), fmaxf(sred[8 + hd], sred[12 + hd]));
        __syncthreads();
        float ex[4];
#pragma unroll
        for (int hd = 0; hd < 4; hd++) {
            ex[hd] = (t < cnt) ? expf(e[hd] - mh[hd]) : 0.f;
            float rv = ex[hd];
#pragma unroll
            for (int off = 32; off; off >>= 1) rv += __shfl_down(rv, off);
            if (lane == 0) sred[wave * 4 + hd] = rv;
        }
        __syncthreads();
#pragma unroll
        for (int hd = 0; hd < 4; hd++) {
            float dh = sred[hd] + sred[4 + hd] + sred[8 + hd] + sred[12 + hd] + 1e-16f;
            if (t < cnt) sal[t * 4 + hd] = ex[hd] / dh;
        }
        __syncthreads();
        for (int e2 = 0; e2 < cnt; e2++) {
            const short* hs = h + (size_t)ssrc[e2] * hst;
            acc0 += sal[e2 * 4 + h0] * bf2f(hs[d0]);
            acc1 += sal[e2 * 4 + h1_] * bf2f(hs[d1]);
            acc2 += sal[e2 * 4 + h2_] * bf2f(hs[d2]);
        }
    } else {
        float mh[4] = {-1e30f, -1e30f, -1e30f, -1e30f};
        for (int p = p0 + t; p < p1; p += 256) {
            int s = csr[p];
#pragma unroll
            for (int hd = 0; hd < 4; hd++) {
                float e = es[s * 4 + hd] + edj[hd];
                e = e > 0.f ? e : 0.2f * e;
                mh[hd] = fmaxf(mh[hd], e);
            }
        }
#pragma unroll
        for (int hd = 0; hd < 4; hd++) sred[hd * 256 + t] = mh[hd];
        __syncthreads();
        for (int s2 = 128; s2; s2 >>= 1) {
            if (t < s2)
#pragma unroll
                for (int hd = 0; hd < 4; hd++)
                    sred[hd * 256 + t] = fmaxf(sred[hd * 256 + t], sred[hd * 256 + t + s2]);
            __syncthreads();
        }
#pragma unroll
        for (int hd = 0; hd < 4; hd++) mh[hd] = sred[hd * 256];
        __syncthreads();
        float sh[4] = {0.f, 0.f, 0.f, 0.f};
        for (int p = p0 + t; p < p1; p += 256) {
            int s = csr[p];
#pragma unroll
            for (int hd = 0; hd < 4; hd++) {
                float e = es[s * 4 + hd] + edj[hd];
                e = e > 0.f ? e : 0.2f * e;
                sh[hd] += expf(e - mh[hd]);
            }
        }
#pragma unroll
        for (int hd = 0; hd < 4; hd++) sred[hd * 256 + t] = sh[hd];
        __syncthreads();
        for (int s2 = 128; s2; s2 >>= 1) {
            if (t < s2)
#pragma unroll
                for (int hd = 0; hd < 4; hd++)
                    sred[hd * 256 + t] += sred[hd * 256 + t + s2];
            __syncthreads();
        }
        float dh[4];
#pragma unroll
        for (int hd = 0; hd < 4; hd++) dh[hd] = sred[hd * 256] + 1e-16f;
        __syncthreads();
        for (int p = p0; p < p1; p += 64) {
            int cn = min(64, p1 - p);
            if (t < cn) {
                int s = csr[p + t];
                ssrc[t] = s;
#pragma unroll
                for (int hd = 0; hd < 4; hd++) {
                    float e = es[s * 4 + hd] + edj[hd];
                    e = e > 0.f ? e : 0.2f * e;
                    sal[t * 4 + hd] = expf(e - mh[hd]) / dh[hd];
                }
            }
            __syncthreads();
            for (int e2 = 0; e2 < cn; e2++) {
                const short* hs = h + (size_t)ssrc[e2] * hst;
                acc0 += sal[e2 * 4 + h0] * bf2f(hs[d0]);
                acc1 += sal[e2 * 4 + h1_] * bf2f(hs[d1]);
                acc2 += sal[e2 * 4 + h2_] * bf2f(hs[d2]);
            }
            __syncthreads();
        }
    }

    if (concat) {
        float v0 = fmaxf(acc0 + gb[d0], 0.f) + rres[(size_t)j * rst + d0];
        float v1 = fmaxf(acc1 + gb[d1], 0.f) + rres[(size_t)j * rst + d1];
        float v2 = fmaxf(acc2 + gb[d2], 0.f) + rres[(size_t)j * rst + d2];
        __syncthreads();
        sred[t] = v0 + v1 + v2; __syncthreads();
        for (int s = 128; s; s >>= 1) { if (t < s) sred[t] += sred[t + s]; __syncthreads(); }
        float mu = sred[0] / 768.f;
        __syncthreads();
        float a0 = v0 - mu, a1 = v1 - mu, a2 = v2 - mu;
        sred[t] = a0 * a0 + a1 * a1 + a2 * a2; __syncthreads();
        for (int s = 128; s; s >>= 1) { if (t < s) sred[t] += sred[t + s]; __syncthreads(); }
        float rs = rsqrtf(sred[0] / 768.f + 1e-5f);
        size_t base = (size_t)j * 768;
        float w0 = a0 * rs * gamma[d0] + beta[d0];
        float w1 = a1 * rs * gamma[d1] + beta[d1];
        float w2 = a2 * rs * gamma[d2] + beta[d2];
        if (outp) { outp[base + d0] = w0; outp[base + d1] = w1; outp[base + d2] = w2; }
        short hh;
        hh = f2bf(w0); ohi[base + d0] = hh; olo[base + d0] = f2bf(w0 - bf2f(hh));
        hh = f2bf(w1); ohi[base + d1] = hh; olo[base + d1] = f2bf(w1 - bf2f(hh));
        hh = f2bf(w2); ohi[base + d2] = hh; olo[base + d2] = f2bf(w2 - bf2f(hh));
    } else {
        accs[d0] = acc0; accs[d1] = acc1; accs[d2] = acc2;
        __syncthreads();
        float val = 0.f;
        if (t < CC)
            val = fmaxf((accs[t] + accs[t + CC] + accs[t + 2 * CC] + accs[t + 3 * CC]) * 0.25f
                        + gb[t], 0.f) + rres[(size_t)j * rst + t];
        __syncthreads();
        sred[t] = (t < CC) ? val : 0.f; __syncthreads();
        for (int s = 128; s; s >>= 1) { if (t < s) sred[t] += sred[t + s]; __syncthreads(); }
        float mu = sred[0] / (float)CC;
        __syncthreads();
        float a = val - mu;
        sred[t] = (t < CC) ? a * a : 0.f; __syncthreads();
        for (int s = 128; s; s >>= 1) { if (t < s) sred[t] += sred[t + s]; __syncthreads(); }
        float rs = rsqrtf(sred[0] / (float)CC + 1e-5f);
        float w = a * rs * ((t < CC) ? gamma[t] : 0.f) + ((t < CC) ? beta[t] : 0.f);
        if (t < CC) {
            size_t idx = (size_t)j * CC + t;
            if (outp) outp[idx] = w;
            if (ohi) {
                short hh = f2bf(w);
                ohi[idx] = hh; olo[idx] = f2bf(w - bf2f(hh));
            }
            accs[t] = w;
        }
        if (fco) {
            __syncthreads();
            if (t < 64) {
#pragma unroll
                for (int n = 0; n < 7; n++) {
                    float p = 0.f;
                    for (int d = t; d < CC; d += 64) p += accs[d] * fcw[d * 7 + n];
#pragma unroll
                    for (int off = 32; off; off >>= 1) p += __shfl_down(p, off);
                    if (t == 0) fco[(size_t)j * 7 + n] = p + fcb[n];
                }
            }
        }
    }
}

extern "C" void kernel_launch(void* const* d_in, const int* in_sizes, int n_in,
                              void* d_out, int out_size, void* d_ws, size_t ws_size,
                              hipStream_t stream)
{
    const float* x     = (const float*)d_in[0];
    const float* bn_g  = (const float*)d_in[1];
    const float* bn_b  = (const float*)d_in[2];
    const float* bn_rm = (const float*)d_in[3];
    const float* bn_rv = (const float*)d_in[4];
    const float* g_w[4]  = {(const float*)d_in[5], (const float*)d_in[9],
                            (const float*)d_in[13], (const float*)d_in[17]};
    const float* g_as[4] = {(const float*)d_in[6], (const float*)d_in[10],
                            (const float*)d_in[14], (const float*)d_in[18]};
    const float* g_ad[4] = {(const float*)d_in[7], (const float*)d_in[11],
                            (const float*)d_in[15], (const float*)d_in[19]};
    const float* g_b[4]  = {(const float*)d_in[8], (const float*)d_in[12],
                            (const float*)d_in[16], (const float*)d_in[20]};
    const float* res1_w = (const float*)d_in[21];
    const float* res1_b = (const float*)d_in[22];
    const float* res2_w = (const float*)d_in[23];
    const float* res2_b = (const float*)d_in[24];
    const float* ln_g[4] = {(const float*)d_in[25], (const float*)d_in[27],
                            (const float*)d_in[29], (const float*)d_in[31]};
    const float* ln_b[4] = {(const float*)d_in[26], (const float*)d_in[28],
                            (const float*)d_in[30], (const float*)d_in[32]};
    const float* fc_w = (const float*)d_in[33];
    const float* fc_b = (const float*)d_in[34];
    float* out = (float*)d_out;

    float* F = (float*)d_ws;
    float* XNF = F; F += 6291456;    // fp32 xn (for exact rescore)
    float* R1  = F; F += 6291456;
    float* H1  = F; F += 6291456;
    float* R2  = F; F += 1572864;
    float* H3  = F; F += 1572864;
    float* ESB = F; F += 262144;
    float* PV  = F; F += 589824;     // 8192 x 72 bf16-candidate values
    short* S = (short*)F;
    short* SAB = S; S += 16777216;   // bf16 panel 4096x4096
    short* SBA = S; S += 16777216;   // bf16 panel 4096x4096
    short* XNH = S; S += 6291456;
    short* XAH = S; S += 6291456;
    short* XAL = S; S += 6291456;
    short* HBH = S; S += 6291456;
    short* WT1H = S; S += 1179648;
    short* WT1L = S; S += 1179648;
    short* WT2H = S; S += 589824;
    short* WT2L = S; S += 589824;
    short* WT3H = S; S += 737280;
    short* WT3L = S; S += 737280;
    short* WT4H = S; S += 147456;
    short* WT4L = S; S += 147456;
    int* I = (int*)S;
    int* NBR    = I; I += NN * KK;
    int* DEG    = I; I += NN;
    int* ROWPTR = I; I += NN + 8;
    int* CUR    = I; I += NN;
    int* MFL    = I; I += NN;
    int* CSR    = I; I += 131072;
    int* PI     = I; I += 589824;    // 8192 x 72 candidate indices
    float* ES[4], *ED[4];
    for (int l = 0; l < 4; l++) { ES[l] = ESB + l * 65536; ED[l] = ES[l] + 32768; }

    // 1. fused BN + rownorm + splits; zero deg + es/ed
    bnorm_kernel<<<NN, 256, 0, stream>>>(x, bn_g, bn_b, bn_rm, bn_rv,
                                         XAH, XAL, XNH, XNF);
    hipMemsetAsync(DEG, 0, NN * sizeof(int), stream);
    hipMemsetAsync(ESB, 0, 262144 * sizeof(float), stream);
    // 2. all weight transposes in one launch
    wtrans6<<<(4 * 589824 + 2 * 147456 + 255) / 256, 256, 0, stream>>>(
        res1_w, WT1H, WT1L,
        g_w[0], WT1H + 768 * 768, WT1L + 768 * 768,
        g_w[1], WT2H, WT2L,
        res2_w, WT3H, WT3L,
        g_w[2], WT3H + 192 * 768, WT3L + 192 * 768,
        g_w[3], WT4H, WT4L);
    // 3. symmetric bf16 sim: pair + merged diag; candidate scan; exact rescore
    mfma_sym<<<dim3(32, 32), 256, 0, stream>>>(XNH, 0, SAB, SBA);
    topk1b_kernel<<<8192, 256, 0, stream>>>(SAB, SBA, PV, PI, 0);
    mfma_sym<<<1056, 256, 0, stream>>>(XNH, 1, SAB, SBA);
    topk1b_kernel<<<8192, 256, 0, stream>>>(SAB, SBA, PV, PI, 1);
    rescore_kernel<<<NN, 256, 0, stream>>>(XNF, PV, PI, NBR);
    // 4. edges -> CSR
    count_kernel<<<NN / 256, 256, 0, stream>>>(NBR, DEG, MFL);
    scan_kernel<<<1, 256, 0, stream>>>(DEG, ROWPTR, CUR);
    fill_kernel<<<NN / 256, 256, 0, stream>>>(NBR, MFL, CUR, CSR);
    // 5. layer 1: [r1(fp32) | h1(bf16)] = xb @ [res1_w | g1_w], es fused
    mfma_nt<<<dim3(12, NN / 128), 256, 0, stream>>>(XAH, XAL, WT1H, WT1L,
        res1_b, 768, R1, 768, HBH, 768, 768,
        g_as[0], g_ad[0], ES[0], ED[0], 768, NN, DD, 1536);
    agg_ln_kernel<<<NN, 256, 0, stream>>>(HBH, 768, ES[0], ED[0], ROWPTR, CSR,
        g_b[0], R1, 768, ln_g[0], ln_b[0], H1, XAH, XAL, HC, 1, nullptr, nullptr, nullptr);
    // 6. layer 2
    mfma_nt<<<dim3(6, NN / 128), 256, 0, stream>>>(XAH, XAL, WT2H, WT2L,
        nullptr, 0, nullptr, 0, HBH, 0, 768,
        g_as[1], g_ad[1], ES[1], ED[1], 0, NN, HC, HC);
    agg_ln_kernel<<<NN, 256, 0, stream>>>(HBH, 768, ES[1], ED[1], ROWPTR, CSR,
        g_b[1], H1, 768, ln_g[1], ln_b[1], nullptr, XAH, XAL, HC, 1, nullptr, nullptr, nullptr);
    // 7. layer 3: [r2(fp32,192) | h3(bf16)] = h2 @ [res2_w | g3_w]
    mfma_nt<<<dim3(8, NN / 128), 256, 0, stream>>>(XAH, XAL, WT3H, WT3L,
        res2_b, 192, R2, 192, HBH, 192, 768,
        g_as[2], g_ad[2], ES[2], ED[2], 192, NN, HC, 960);
    agg_ln_kernel<<<NN, 256, 0, stream>>>(HBH, 768, ES[2], ED[2], ROWPTR, CSR,
        g_b[2], R2, 192, ln_g[2], ln_b[2], H3, XAH, XAL, CC, 0, nullptr, nullptr, nullptr);
    // 8. layer 4 (K=192) + fused final FC
    mfma_nt<<<dim3(6, NN / 128), 256, 0, stream>>>(XAH, XAL, WT4H, WT4L,
        nullptr, 0, nullptr, 0, HBH, 0, 768,
        g_as[3], g_ad[3], ES[3], ED[3], 0, NN, CC, HC);
    agg_ln_kernel<<<NN, 256, 0, stream>>>(HBH, 768, ES[3], ED[3], ROWPTR, CSR,
        g_b[3], H3, 192, ln_g[3], ln_b[3], nullptr, nullptr, nullptr, CC, 0, fc_w, fc_b, out);
}